// Round 2
// baseline (2602.958 us; speedup 1.0000x reference)
//
#include <hip/hip_runtime.h>
#include <math.h>

#define BATCH 4
#define NPTS 1024
#define KNN 20
#define EPS 1e-5f
#define FEATC 2048

// ---------------- xx: per-point squared norm ----------------
__global__ void xx_kernel(const float* __restrict__ x, int Cin, size_t bstride,
                          float* __restrict__ xx) {
    int t = blockIdx.x * blockDim.x + threadIdx.x;  // b*NPTS + n
    if (t >= BATCH * NPTS) return;
    int b = t / NPTS, n = t % NPTS;
    const float* xb = x + (size_t)b * bstride;
    float s = 0.f;
    for (int c = 0; c < Cin; ++c) { float v = xb[(size_t)c * NPTS + n]; s += v * v; }
    xx[t] = s;
}

// ---------------- Gram matrix: G[b][n][m] = dot(x_n, x_m) ----------------
#define TS 64
#define KC 16
__global__ void gram_kernel(const float* __restrict__ x, int Cin, size_t bstride,
                            float* __restrict__ G) {
    // grid: (NPTS/TS, NPTS/TS, BATCH); block 256
    int b = blockIdx.z;
    int n0 = blockIdx.y * TS;
    int m0 = blockIdx.x * TS;
    const float* xb = x + (size_t)b * bstride;
    __shared__ float As[KC][TS];
    __shared__ float Bs[KC][TS];
    int tid = threadIdx.x;
    int tn = tid % 16, tm = tid / 16;  // 4x4 outputs per thread
    float acc[4][4] = {};
    for (int c0 = 0; c0 < Cin; c0 += KC) {
        for (int i = tid; i < KC * TS; i += 256) {
            int cc = i / TS, nn = i % TS;
            float av = 0.f, bv = 0.f;
            if (c0 + cc < Cin) {
                av = xb[(size_t)(c0 + cc) * NPTS + n0 + nn];
                bv = xb[(size_t)(c0 + cc) * NPTS + m0 + nn];
            }
            As[cc][nn] = av;
            Bs[cc][nn] = bv;
        }
        __syncthreads();
        for (int cc = 0; cc < KC; ++cc) {
            float a[4], bb[4];
#pragma unroll
            for (int i = 0; i < 4; i++) a[i] = As[cc][tn * 4 + i];
#pragma unroll
            for (int j = 0; j < 4; j++) bb[j] = Bs[cc][tm * 4 + j];
#pragma unroll
            for (int i = 0; i < 4; i++)
#pragma unroll
                for (int j = 0; j < 4; j++) acc[i][j] += a[i] * bb[j];
        }
        __syncthreads();
    }
    float* Gb = G + (size_t)b * NPTS * NPTS;
#pragma unroll
    for (int i = 0; i < 4; i++)
#pragma unroll
        for (int j = 0; j < 4; j++)
            Gb[(size_t)(n0 + tn * 4 + i) * NPTS + m0 + tm * 4 + j] = acc[i][j];
}

// ---------------- top-K selection per row ----------------
__global__ void topk_kernel(const float* __restrict__ G, const float* __restrict__ xx,
                            int* __restrict__ idx) {
    // grid BATCH*NPTS, block 256
    int t = blockIdx.x;
    int b = t / NPTS, n = t % NPTS;
    const float* Gr = G + (size_t)b * NPTS * NPTS + (size_t)n * NPTS;
    const float* xxb = xx + b * NPTS;
    __shared__ float dist[NPTS];
    __shared__ float rv[256];
    __shared__ int ri[256];
    int tid = threadIdx.x;
    float xxn = xxb[n];
    for (int m = tid; m < NPTS; m += 256)
        dist[m] = (2.f * Gr[m] - xxn) - xxb[m];  // matches ref op order
    __syncthreads();
    int* out = idx + (size_t)t * KNN;
    for (int k = 0; k < KNN; ++k) {
        float bv = -INFINITY; int bi = NPTS;
        for (int m = tid; m < NPTS; m += 256) {
            float v = dist[m];
            if (v > bv || (v == bv && m < bi)) { bv = v; bi = m; }
        }
        rv[tid] = bv; ri[tid] = bi;
        __syncthreads();
        for (int s = 128; s > 0; s >>= 1) {
            if (tid < s) {
                float v2 = rv[tid + s]; int i2 = ri[tid + s];
                if (v2 > rv[tid] || (v2 == rv[tid] && i2 < ri[tid])) { rv[tid] = v2; ri[tid] = i2; }
            }
            __syncthreads();
        }
        if (tid == 0) { out[k] = ri[0]; dist[ri[0]] = -INFINITY; }
        __syncthreads();
    }
}

// ---------------- p/q per-point transforms ----------------
__global__ void pq_kernel(const float* __restrict__ x, int Cin, size_t bstride,
                          const float* __restrict__ W, int Cout,
                          float* __restrict__ p, float* __restrict__ q) {
    // grid: (Cout/64, NPTS/64, BATCH); block 256 = 64 o-lanes x 4 groups of 16 points
    int b = blockIdx.z;
    int o = blockIdx.x * 64 + (threadIdx.x & 63);
    int g = threadIdx.x >> 6;
    int n0 = blockIdx.y * 64 + g * 16;
    const float* xb = x + (size_t)b * bstride;
    const float* Wr = W + (size_t)o * 2 * Cin;
    float accp[16] = {}, accq[16] = {};
    for (int c = 0; c < Cin; ++c) {
        float w1 = Wr[c], w2 = Wr[Cin + c];
        float wq = w2 - w1;
        const float* xc = xb + (size_t)c * NPTS + n0;
#pragma unroll
        for (int i = 0; i < 16; ++i) {
            float xv = xc[i];
            accp[i] += w1 * xv;
            accq[i] += wq * xv;
        }
    }
#pragma unroll
    for (int i = 0; i < 16; ++i) {
        size_t base = ((size_t)b * NPTS + n0 + i) * Cout + o;
        p[base] = accp[i];
        q[base] = accq[i];
    }
}

// ---------------- stats + max/min over K (deterministic: per-block partials) ----------------
template <int COUT>
__global__ void stats_kernel(const float* __restrict__ p, const float* __restrict__ q,
                             const int* __restrict__ idx,
                             float* __restrict__ vmax, float* __restrict__ vmin,
                             float* __restrict__ partials) {
    constexpr int CA = (COUT < 256) ? COUT : 256;
    constexpr int PP = 256 / CA;
    constexpr int CH = COUT / CA;
    constexpr int NCHUNK = 16;
    int bid = blockIdx.x;
    int b = bid / (NPTS / NCHUNK);
    int n0 = (bid % (NPTS / NCHUNK)) * NCHUNK;
    int c = threadIdx.x % CA;
    int sub = threadIdx.x / CA;
    float s[CH] = {}, ss[CH] = {};
    for (int nl = sub; nl < NCHUNK; nl += PP) {
        int n = n0 + nl;
        size_t nb = (size_t)b * NPTS + n;
        const int* ix = idx + nb * KNN;
        float qv[CH], mx[CH], mn[CH];
#pragma unroll
        for (int j = 0; j < CH; j++) {
            qv[j] = q[nb * COUT + c + j * CA];
            mx[j] = -INFINITY; mn[j] = INFINITY;
        }
        for (int k = 0; k < KNN; ++k) {
            int m = ix[k];
            size_t pb = ((size_t)b * NPTS + m) * COUT + c;
#pragma unroll
            for (int j = 0; j < CH; j++) {
                float v = p[pb + j * CA] + qv[j];
                mx[j] = fmaxf(mx[j], v);
                mn[j] = fminf(mn[j], v);
                s[j] += v;
                ss[j] += v * v;
            }
        }
#pragma unroll
        for (int j = 0; j < CH; j++) {
            vmax[nb * COUT + c + j * CA] = mx[j];
            vmin[nb * COUT + c + j * CA] = mn[j];
        }
    }
    // deterministic block-level reduction over the PP sub-threads per channel
    __shared__ float red[256];
    float* outp = partials + (size_t)bid * 2 * COUT;
#pragma unroll
    for (int j = 0; j < CH; j++) {
        red[threadIdx.x] = s[j];
        __syncthreads();
        for (int st = PP / 2; st > 0; st >>= 1) {
            if (sub < st) red[threadIdx.x] += red[threadIdx.x + st * CA];
            __syncthreads();
        }
        if (sub == 0) outp[c + j * CA] = red[c];
        __syncthreads();
        red[threadIdx.x] = ss[j];
        __syncthreads();
        for (int st = PP / 2; st > 0; st >>= 1) {
            if (sub < st) red[threadIdx.x] += red[threadIdx.x + st * CA];
            __syncthreads();
        }
        if (sub == 0) outp[COUT + c + j * CA] = red[c];
        __syncthreads();
    }
}

// ---------------- BN scale/shift from partials (deterministic serial reduce) ----------------
__global__ void scaleshift_kernel(const float* __restrict__ partials, const float* __restrict__ g,
                                  const float* __restrict__ beta, int Cout, int nblk,
                                  float* __restrict__ sc) {
    int c = blockIdx.x * 256 + threadIdx.x;
    if (c >= Cout) return;
    float s0 = 0.f, s1 = 0.f;
    for (int b = 0; b < nblk; ++b) {
        s0 += partials[(size_t)b * 2 * Cout + c];
        s1 += partials[(size_t)b * 2 * Cout + Cout + c];
    }
    float cnt = (float)(BATCH * NPTS * KNN);
    float mean = s0 / cnt;
    float var = s1 / cnt - mean * mean;
    float s = g[c] * rsqrtf(var + EPS);
    sc[c] = s;
    sc[Cout + c] = beta[c] - mean * s;
}

// ---------------- apply BN+leaky, transpose to (B, C, N) feat ----------------
__global__ void apply_kernel(const float* __restrict__ vmax, const float* __restrict__ vmin,
                             const float* __restrict__ sc, int Cout, int choff,
                             float* __restrict__ feat) {
    // grid: (Cout/32, NPTS/32, BATCH); block 256 = 32x8
    __shared__ float tile[32][33];
    int b = blockIdx.z;
    int c0 = blockIdx.x * 32, n0 = blockIdx.y * 32;
    int tx = threadIdx.x % 32, ty = threadIdx.x / 32;
    for (int i = ty; i < 32; i += 8) {
        int c = c0 + tx, n = n0 + i;
        float s = sc[c], sh = sc[Cout + c];
        size_t off = ((size_t)b * NPTS + n) * Cout + c;
        float v = (s >= 0.f) ? vmax[off] : vmin[off];
        v = s * v + sh;
        tile[i][tx] = (v > 0.f) ? v : 0.2f * v;
    }
    __syncthreads();
    for (int i = ty; i < 32; i += 8) {
        int c = c0 + i, n = n0 + tx;
        feat[((size_t)b * FEATC + choff + c) * NPTS + n] = tile[tx][i];
    }
}

// ---------------- pooling: max and mean over N ----------------
__global__ void pool_kernel(const float* __restrict__ feat, float* __restrict__ pooled) {
    // grid BATCH*FEATC, block 256
    int t = blockIdx.x;
    int b = t >> 11, c = t & (FEATC - 1);
    const float* row = feat + (size_t)t * NPTS;
    int tid = threadIdx.x;
    float mx = -INFINITY, sm = 0.f;
    for (int n = tid; n < NPTS; n += 256) { float v = row[n]; mx = fmaxf(mx, v); sm += v; }
    __shared__ float smx[256], ssm[256];
    smx[tid] = mx; ssm[tid] = sm;
    __syncthreads();
    for (int s = 128; s > 0; s >>= 1) {
        if (tid < s) { smx[tid] = fmaxf(smx[tid], smx[tid + s]); ssm[tid] += ssm[tid + s]; }
        __syncthreads();
    }
    if (tid == 0) {
        pooled[b * 4096 + c] = smx[0];
        pooled[b * 4096 + 2048 + c] = ssm[0] * (1.f / NPTS);
    }
}

// ---------------- final GEMV + batch-BN + leaky ----------------
__global__ void final_kernel(const float* __restrict__ pooled, const float* __restrict__ Wm,
                             const float* __restrict__ bm, const float* __restrict__ gm,
                             const float* __restrict__ betam, float* __restrict__ out) {
    // grid 512, block 256
    int o = blockIdx.x;
    int tid = threadIdx.x;
    float acc[BATCH] = {};
    for (int t = tid; t < 4096; t += 256) {
        float w = Wm[(size_t)o * 4096 + t];
#pragma unroll
        for (int b = 0; b < BATCH; b++) acc[b] += w * pooled[b * 4096 + t];
    }
    __shared__ float red[256];
    float zb[BATCH];
    for (int b = 0; b < BATCH; b++) {
        red[tid] = acc[b];
        __syncthreads();
        for (int s = 128; s > 0; s >>= 1) {
            if (tid < s) red[tid] += red[tid + s];
            __syncthreads();
        }
        zb[b] = red[0];
        __syncthreads();
    }
    if (tid == 0) {
        float z[BATCH];
        float mean = 0.f;
        for (int b = 0; b < BATCH; b++) { z[b] = zb[b] + bm[o]; mean += z[b]; }
        mean *= (1.f / BATCH);
        float var = 0.f;
        for (int b = 0; b < BATCH; b++) { float d = z[b] - mean; var += d * d; }
        var *= (1.f / BATCH);
        float s = gm[o] * rsqrtf(var + EPS);
        for (int b = 0; b < BATCH; b++) {
            float v = (z[b] - mean) * s + betam[o];
            out[b * 512 + o] = (v > 0.f) ? v : 0.2f * v;
        }
    }
}

extern "C" void kernel_launch(void* const* d_in, const int* in_sizes, int n_in,
                              void* d_out, int out_size, void* d_ws, size_t ws_size,
                              hipStream_t stream) {
    const float* x = (const float*)d_in[0];
    const float* Wm = (const float*)d_in[19];
    const float* bm = (const float*)d_in[20];
    const float* gm = (const float*)d_in[21];
    const float* betam = (const float*)d_in[22];
    float* out = (float*)d_out;

    char* ws = (char*)d_ws;
    float* G        = (float*)(ws);                        // 16 MB (shared with p)
    float* p        = G;
    float* q        = (float*)(ws + (size_t)(16 << 20));   // 16 MB
    float* vmax     = (float*)(ws + (size_t)(32 << 20));   // 16 MB
    float* vmin     = (float*)(ws + (size_t)(48 << 20));   // 16 MB
    float* feat     = (float*)(ws + (size_t)(64 << 20));   // 32 MB
    int*   idx      = (int*)  (ws + (size_t)(96 << 20));   // 320 KB
    float* xx       = (float*)(ws + (size_t)(96 << 20) + (512 << 10));  // 16 KB
    float* sc       = (float*)(ws + (size_t)(96 << 20) + (512 << 10) + (96 << 10)); // 8 KB
    float* pooled   = (float*)(ws + (size_t)(96 << 20) + (640 << 10)); // 64 KB
    float* partials = (float*)(ws + (size_t)(97 << 20));   // 2 MB (256 blocks x 2*Cout)

    const int cins[6]   = {8, 64, 64, 128, 256, 512};
    const int couts[6]  = {64, 64, 128, 256, 512, 1024};
    const int choffs[6] = {0, 64, 128, 256, 512, 1024};

    const float* xin = x;
    size_t bstride = (size_t)8 * NPTS;
    const int NBLK = BATCH * (NPTS / 16);  // 256 stats blocks

    for (int L = 0; L < 6; ++L) {
        int Cin = cins[L], Cout = couts[L], choff = choffs[L];
        const float* W = (const float*)d_in[1 + 3 * L];
        const float* g = (const float*)d_in[2 + 3 * L];
        const float* bb = (const float*)d_in[3 + 3 * L];

        xx_kernel<<<(BATCH * NPTS + 255) / 256, 256, 0, stream>>>(xin, Cin, bstride, xx);
        gram_kernel<<<dim3(NPTS / TS, NPTS / TS, BATCH), 256, 0, stream>>>(xin, Cin, bstride, G);
        topk_kernel<<<BATCH * NPTS, 256, 0, stream>>>(G, xx, idx);
        pq_kernel<<<dim3(Cout / 64, NPTS / 64, BATCH), 256, 0, stream>>>(xin, Cin, bstride, W, Cout, p, q);
        switch (Cout) {
            case 64:   stats_kernel<64>  <<<NBLK, 256, 0, stream>>>(p, q, idx, vmax, vmin, partials); break;
            case 128:  stats_kernel<128> <<<NBLK, 256, 0, stream>>>(p, q, idx, vmax, vmin, partials); break;
            case 256:  stats_kernel<256> <<<NBLK, 256, 0, stream>>>(p, q, idx, vmax, vmin, partials); break;
            case 512:  stats_kernel<512> <<<NBLK, 256, 0, stream>>>(p, q, idx, vmax, vmin, partials); break;
            case 1024: stats_kernel<1024><<<NBLK, 256, 0, stream>>>(p, q, idx, vmax, vmin, partials); break;
        }
        scaleshift_kernel<<<(Cout + 255) / 256, 256, 0, stream>>>(partials, g, bb, Cout, NBLK, sc);
        apply_kernel<<<dim3(Cout / 32, NPTS / 32, BATCH), 256, 0, stream>>>(vmax, vmin, sc, Cout, choff, feat);

        xin = feat + (size_t)choff * NPTS;
        bstride = (size_t)FEATC * NPTS;
    }

    pool_kernel<<<BATCH * FEATC, 256, 0, stream>>>(feat, pooled);
    final_kernel<<<512, 256, 0, stream>>>(pooled, Wm, bm, gm, betam, out);
}

// Round 3
// 1963.498 us; speedup vs baseline: 1.3257x; 1.3257x over previous
//
#include <hip/hip_runtime.h>
#include <math.h>

#define BATCH 4
#define NPTS 1024
#define KNN 20
#define EPS 1e-5f
#define FEATC 2048

// ---------------- xx: per-point squared norm ----------------
__global__ void xx_kernel(const float* __restrict__ x, int Cin, size_t bstride,
                          float* __restrict__ xx) {
    int t = blockIdx.x * blockDim.x + threadIdx.x;  // b*NPTS + n
    if (t >= BATCH * NPTS) return;
    int b = t / NPTS, n = t % NPTS;
    const float* xb = x + (size_t)b * bstride;
    float s = 0.f;
    for (int c = 0; c < Cin; ++c) { float v = xb[(size_t)c * NPTS + n]; s += v * v; }
    xx[t] = s;
}

// ---------------- Gram matrix: G[b][n][m] = dot(x_n, x_m) ----------------
#define TS 64
#define KC 16
__global__ void gram_kernel(const float* __restrict__ x, int Cin, size_t bstride,
                            float* __restrict__ G) {
    // grid: (NPTS/TS, NPTS/TS, BATCH); block 256
    int b = blockIdx.z;
    int n0 = blockIdx.y * TS;
    int m0 = blockIdx.x * TS;
    const float* xb = x + (size_t)b * bstride;
    __shared__ float As[KC][TS];
    __shared__ float Bs[KC][TS];
    int tid = threadIdx.x;
    int tn = tid % 16, tm = tid / 16;  // 4x4 outputs per thread
    float acc[4][4] = {};
    for (int c0 = 0; c0 < Cin; c0 += KC) {
        for (int i = tid; i < KC * TS; i += 256) {
            int cc = i / TS, nn = i % TS;
            float av = 0.f, bv = 0.f;
            if (c0 + cc < Cin) {
                av = xb[(size_t)(c0 + cc) * NPTS + n0 + nn];
                bv = xb[(size_t)(c0 + cc) * NPTS + m0 + nn];
            }
            As[cc][nn] = av;
            Bs[cc][nn] = bv;
        }
        __syncthreads();
        for (int cc = 0; cc < KC; ++cc) {
            float a[4], bb[4];
#pragma unroll
            for (int i = 0; i < 4; i++) a[i] = As[cc][tn * 4 + i];
#pragma unroll
            for (int j = 0; j < 4; j++) bb[j] = Bs[cc][tm * 4 + j];
#pragma unroll
            for (int i = 0; i < 4; i++)
#pragma unroll
                for (int j = 0; j < 4; j++) acc[i][j] += a[i] * bb[j];
        }
        __syncthreads();
    }
    float* Gb = G + (size_t)b * NPTS * NPTS;
#pragma unroll
    for (int i = 0; i < 4; i++)
#pragma unroll
        for (int j = 0; j < 4; j++)
            Gb[(size_t)(n0 + tn * 4 + i) * NPTS + m0 + tm * 4 + j] = acc[i][j];
}

// ---------------- top-K selection per row ----------------
__global__ void topk_kernel(const float* __restrict__ G, const float* __restrict__ xx,
                            int* __restrict__ idx) {
    // grid BATCH*NPTS, block 256
    int t = blockIdx.x;
    int b = t / NPTS, n = t % NPTS;
    const float* Gr = G + (size_t)b * NPTS * NPTS + (size_t)n * NPTS;
    const float* xxb = xx + b * NPTS;
    __shared__ float dist[NPTS];
    __shared__ float rv[256];
    __shared__ int ri[256];
    int tid = threadIdx.x;
    float xxn = xxb[n];
    for (int m = tid; m < NPTS; m += 256)
        dist[m] = (2.f * Gr[m] - xxn) - xxb[m];  // matches ref op order
    __syncthreads();
    int* out = idx + (size_t)t * KNN;
    for (int k = 0; k < KNN; ++k) {
        float bv = -INFINITY; int bi = NPTS;
        for (int m = tid; m < NPTS; m += 256) {
            float v = dist[m];
            if (v > bv || (v == bv && m < bi)) { bv = v; bi = m; }
        }
        rv[tid] = bv; ri[tid] = bi;
        __syncthreads();
        for (int s = 128; s > 0; s >>= 1) {
            if (tid < s) {
                float v2 = rv[tid + s]; int i2 = ri[tid + s];
                if (v2 > rv[tid] || (v2 == rv[tid] && i2 < ri[tid])) { rv[tid] = v2; ri[tid] = i2; }
            }
            __syncthreads();
        }
        if (tid == 0) { out[k] = ri[0]; dist[ri[0]] = -INFINITY; }
        __syncthreads();
    }
}

// ---------------- p/q: tiled GEMM  p = W1*x, q = (W2-W1)*x ----------------
// grid: (Cout/TOUT, NPTS/64, BATCH); block 256 = 16 (o-groups) x 16 (n-groups)
template <int TOUT>
__global__ void pq_gemm_kernel(const float* __restrict__ x, int Cin, size_t bstride,
                               const float* __restrict__ W, int Cout,
                               float* __restrict__ p, float* __restrict__ q) {
    constexpr int RO = TOUT / 16;  // outputs per thread in o (4 or 8)
    int b = blockIdx.z;
    int o0 = blockIdx.x * TOUT;
    int n0 = blockIdx.y * 64;
    const float* xb = x + (size_t)b * bstride;
    __shared__ float W1s[KC][TOUT];
    __shared__ float WQs[KC][TOUT];
    __shared__ float Xs[KC][64];
    int tid = threadIdx.x;
    int tn = tid % 16;  // o group: o = o0 + tn*RO + i
    int tm = tid / 16;  // n group: n = n0 + tm*4 + j
    float accp[RO][4] = {};
    float accq[RO][4] = {};

    for (int c0 = 0; c0 < Cin; c0 += KC) {
        // ---- stage X chunk: KC x 64 floats, float4 per thread ----
        {
            int i = tid * 4;
            int cc = i >> 6, nn = i & 63;
            float4 v = make_float4(0.f, 0.f, 0.f, 0.f);
            if (c0 + cc < Cin)
                v = *(const float4*)(xb + (size_t)(c0 + cc) * NPTS + n0 + nn);
            *(float4*)(&Xs[cc][nn]) = v;
        }
        // ---- stage W chunk transposed: W1s/WQs[cc][row] ----
        {
            constexpr int PARTS = 256 / TOUT;        // 4 (TOUT=64) or 2 (TOUT=128)
            constexpr int CPW = KC / PARTS;          // cc per thread: 4 or 8
            int r = tid % TOUT;
            int cg = (tid / TOUT) * CPW;
            const float* Wr = W + (size_t)(o0 + r) * 2 * Cin;
#pragma unroll
            for (int u = 0; u < CPW; u += 4) {
                int cc = cg + u;
                float4 w1 = make_float4(0.f, 0.f, 0.f, 0.f);
                float4 w2 = make_float4(0.f, 0.f, 0.f, 0.f);
                if (c0 + cc < Cin) {
                    w1 = *(const float4*)(Wr + c0 + cc);
                    w2 = *(const float4*)(Wr + Cin + c0 + cc);
                }
                W1s[cc + 0][r] = w1.x; WQs[cc + 0][r] = w2.x - w1.x;
                W1s[cc + 1][r] = w1.y; WQs[cc + 1][r] = w2.y - w1.y;
                W1s[cc + 2][r] = w1.z; WQs[cc + 2][r] = w2.z - w1.z;
                W1s[cc + 3][r] = w1.w; WQs[cc + 3][r] = w2.w - w1.w;
            }
        }
        __syncthreads();
#pragma unroll
        for (int cc = 0; cc < KC; ++cc) {
            float4 xv = *(const float4*)(&Xs[cc][tm * 4]);
            float w1[RO], wq[RO];
#pragma unroll
            for (int g = 0; g < RO; g += 4) {
                float4 a = *(const float4*)(&W1s[cc][tn * RO + g]);
                w1[g + 0] = a.x; w1[g + 1] = a.y; w1[g + 2] = a.z; w1[g + 3] = a.w;
                float4 aq = *(const float4*)(&WQs[cc][tn * RO + g]);
                wq[g + 0] = aq.x; wq[g + 1] = aq.y; wq[g + 2] = aq.z; wq[g + 3] = aq.w;
            }
            float xj[4] = {xv.x, xv.y, xv.z, xv.w};
#pragma unroll
            for (int i = 0; i < RO; i++)
#pragma unroll
                for (int j = 0; j < 4; j++) {
                    accp[i][j] += w1[i] * xj[j];
                    accq[i][j] += wq[i] * xj[j];
                }
        }
        __syncthreads();
    }
    // ---- write out: for each of 4 n rows, RO consecutive o floats ----
#pragma unroll
    for (int j = 0; j < 4; j++) {
        int n = n0 + tm * 4 + j;
        size_t base = ((size_t)b * NPTS + n) * Cout + o0 + tn * RO;
#pragma unroll
        for (int g = 0; g < RO; g += 4) {
            float4 vp = make_float4(accp[g + 0][j], accp[g + 1][j], accp[g + 2][j], accp[g + 3][j]);
            float4 vq = make_float4(accq[g + 0][j], accq[g + 1][j], accq[g + 2][j], accq[g + 3][j]);
            *(float4*)(p + base + g) = vp;
            *(float4*)(q + base + g) = vq;
        }
    }
}

// ---------------- stats + max/min over K (deterministic: per-block partials) ----------------
template <int COUT>
__global__ void stats_kernel(const float* __restrict__ p, const float* __restrict__ q,
                             const int* __restrict__ idx,
                             float* __restrict__ vmax, float* __restrict__ vmin,
                             float* __restrict__ partials) {
    constexpr int CA = (COUT < 256) ? COUT : 256;
    constexpr int PP = 256 / CA;
    constexpr int CH = COUT / CA;
    constexpr int NCHUNK = 16;
    int bid = blockIdx.x;
    int b = bid / (NPTS / NCHUNK);
    int n0 = (bid % (NPTS / NCHUNK)) * NCHUNK;
    int c = threadIdx.x % CA;
    int sub = threadIdx.x / CA;
    float s[CH] = {}, ss[CH] = {};
    for (int nl = sub; nl < NCHUNK; nl += PP) {
        int n = n0 + nl;
        size_t nb = (size_t)b * NPTS + n;
        const int* ix = idx + nb * KNN;
        float qv[CH], mx[CH], mn[CH];
#pragma unroll
        for (int j = 0; j < CH; j++) {
            qv[j] = q[nb * COUT + c + j * CA];
            mx[j] = -INFINITY; mn[j] = INFINITY;
        }
        for (int k = 0; k < KNN; ++k) {
            int m = ix[k];
            size_t pb = ((size_t)b * NPTS + m) * COUT + c;
#pragma unroll
            for (int j = 0; j < CH; j++) {
                float v = p[pb + j * CA] + qv[j];
                mx[j] = fmaxf(mx[j], v);
                mn[j] = fminf(mn[j], v);
                s[j] += v;
                ss[j] += v * v;
            }
        }
#pragma unroll
        for (int j = 0; j < CH; j++) {
            vmax[nb * COUT + c + j * CA] = mx[j];
            vmin[nb * COUT + c + j * CA] = mn[j];
        }
    }
    // deterministic block-level reduction over the PP sub-threads per channel
    __shared__ float red[256];
    float* outp = partials + (size_t)bid * 2 * COUT;
#pragma unroll
    for (int j = 0; j < CH; j++) {
        red[threadIdx.x] = s[j];
        __syncthreads();
        for (int st = PP / 2; st > 0; st >>= 1) {
            if (sub < st) red[threadIdx.x] += red[threadIdx.x + st * CA];
            __syncthreads();
        }
        if (sub == 0) outp[c + j * CA] = red[c];
        __syncthreads();
        red[threadIdx.x] = ss[j];
        __syncthreads();
        for (int st = PP / 2; st > 0; st >>= 1) {
            if (sub < st) red[threadIdx.x] += red[threadIdx.x + st * CA];
            __syncthreads();
        }
        if (sub == 0) outp[COUT + c + j * CA] = red[c];
        __syncthreads();
    }
}

// ---------------- BN scale/shift from partials (deterministic serial reduce) ----------------
__global__ void scaleshift_kernel(const float* __restrict__ partials, const float* __restrict__ g,
                                  const float* __restrict__ beta, int Cout, int nblk,
                                  float* __restrict__ sc) {
    int c = blockIdx.x * 256 + threadIdx.x;
    if (c >= Cout) return;
    float s0 = 0.f, s1 = 0.f;
    for (int b = 0; b < nblk; ++b) {
        s0 += partials[(size_t)b * 2 * Cout + c];
        s1 += partials[(size_t)b * 2 * Cout + Cout + c];
    }
    float cnt = (float)(BATCH * NPTS * KNN);
    float mean = s0 / cnt;
    float var = s1 / cnt - mean * mean;
    float s = g[c] * rsqrtf(var + EPS);
    sc[c] = s;
    sc[Cout + c] = beta[c] - mean * s;
}

// ---------------- apply BN+leaky, transpose to (B, C, N) feat ----------------
__global__ void apply_kernel(const float* __restrict__ vmax, const float* __restrict__ vmin,
                             const float* __restrict__ sc, int Cout, int choff,
                             float* __restrict__ feat) {
    // grid: (Cout/32, NPTS/32, BATCH); block 256 = 32x8
    __shared__ float tile[32][33];
    int b = blockIdx.z;
    int c0 = blockIdx.x * 32, n0 = blockIdx.y * 32;
    int tx = threadIdx.x % 32, ty = threadIdx.x / 32;
    for (int i = ty; i < 32; i += 8) {
        int c = c0 + tx, n = n0 + i;
        float s = sc[c], sh = sc[Cout + c];
        size_t off = ((size_t)b * NPTS + n) * Cout + c;
        float v = (s >= 0.f) ? vmax[off] : vmin[off];
        v = s * v + sh;
        tile[i][tx] = (v > 0.f) ? v : 0.2f * v;
    }
    __syncthreads();
    for (int i = ty; i < 32; i += 8) {
        int c = c0 + i, n = n0 + tx;
        feat[((size_t)b * FEATC + choff + c) * NPTS + n] = tile[tx][i];
    }
}

// ---------------- pooling: max and mean over N ----------------
__global__ void pool_kernel(const float* __restrict__ feat, float* __restrict__ pooled) {
    // grid BATCH*FEATC, block 256
    int t = blockIdx.x;
    int b = t >> 11, c = t & (FEATC - 1);
    const float* row = feat + (size_t)t * NPTS;
    int tid = threadIdx.x;
    float mx = -INFINITY, sm = 0.f;
    for (int n = tid; n < NPTS; n += 256) { float v = row[n]; mx = fmaxf(mx, v); sm += v; }
    __shared__ float smx[256], ssm[256];
    smx[tid] = mx; ssm[tid] = sm;
    __syncthreads();
    for (int s = 128; s > 0; s >>= 1) {
        if (tid < s) { smx[tid] = fmaxf(smx[tid], smx[tid + s]); ssm[tid] += ssm[tid + s]; }
        __syncthreads();
    }
    if (tid == 0) {
        pooled[b * 4096 + c] = smx[0];
        pooled[b * 4096 + 2048 + c] = ssm[0] * (1.f / NPTS);
    }
}

// ---------------- final GEMV + batch-BN + leaky ----------------
__global__ void final_kernel(const float* __restrict__ pooled, const float* __restrict__ Wm,
                             const float* __restrict__ bm, const float* __restrict__ gm,
                             const float* __restrict__ betam, float* __restrict__ out) {
    // grid 512, block 256
    int o = blockIdx.x;
    int tid = threadIdx.x;
    float acc[BATCH] = {};
    for (int t = tid; t < 4096; t += 256) {
        float w = Wm[(size_t)o * 4096 + t];
#pragma unroll
        for (int b = 0; b < BATCH; b++) acc[b] += w * pooled[b * 4096 + t];
    }
    __shared__ float red[256];
    float zb[BATCH];
    for (int b = 0; b < BATCH; b++) {
        red[tid] = acc[b];
        __syncthreads();
        for (int s = 128; s > 0; s >>= 1) {
            if (tid < s) red[tid] += red[tid + s];
            __syncthreads();
        }
        zb[b] = red[0];
        __syncthreads();
    }
    if (tid == 0) {
        float z[BATCH];
        float mean = 0.f;
        for (int b = 0; b < BATCH; b++) { z[b] = zb[b] + bm[o]; mean += z[b]; }
        mean *= (1.f / BATCH);
        float var = 0.f;
        for (int b = 0; b < BATCH; b++) { float d = z[b] - mean; var += d * d; }
        var *= (1.f / BATCH);
        float s = gm[o] * rsqrtf(var + EPS);
        for (int b = 0; b < BATCH; b++) {
            float v = (z[b] - mean) * s + betam[o];
            out[b * 512 + o] = (v > 0.f) ? v : 0.2f * v;
        }
    }
}

extern "C" void kernel_launch(void* const* d_in, const int* in_sizes, int n_in,
                              void* d_out, int out_size, void* d_ws, size_t ws_size,
                              hipStream_t stream) {
    const float* x = (const float*)d_in[0];
    const float* Wm = (const float*)d_in[19];
    const float* bm = (const float*)d_in[20];
    const float* gm = (const float*)d_in[21];
    const float* betam = (const float*)d_in[22];
    float* out = (float*)d_out;

    char* ws = (char*)d_ws;
    float* G        = (float*)(ws);                        // 16 MB (shared with p)
    float* p        = G;
    float* q        = (float*)(ws + (size_t)(16 << 20));   // 16 MB
    float* vmax     = (float*)(ws + (size_t)(32 << 20));   // 16 MB
    float* vmin     = (float*)(ws + (size_t)(48 << 20));   // 16 MB
    float* feat     = (float*)(ws + (size_t)(64 << 20));   // 32 MB
    int*   idx      = (int*)  (ws + (size_t)(96 << 20));   // 320 KB
    float* xx       = (float*)(ws + (size_t)(96 << 20) + (512 << 10));  // 16 KB
    float* sc       = (float*)(ws + (size_t)(96 << 20) + (512 << 10) + (96 << 10)); // 8 KB
    float* pooled   = (float*)(ws + (size_t)(96 << 20) + (640 << 10)); // 64 KB
    float* partials = (float*)(ws + (size_t)(97 << 20));   // 2 MB (256 blocks x 2*Cout)

    const int cins[6]   = {8, 64, 64, 128, 256, 512};
    const int couts[6]  = {64, 64, 128, 256, 512, 1024};
    const int choffs[6] = {0, 64, 128, 256, 512, 1024};

    const float* xin = x;
    size_t bstride = (size_t)8 * NPTS;
    const int NBLK = BATCH * (NPTS / 16);  // 256 stats blocks

    for (int L = 0; L < 6; ++L) {
        int Cin = cins[L], Cout = couts[L], choff = choffs[L];
        const float* W = (const float*)d_in[1 + 3 * L];
        const float* g = (const float*)d_in[2 + 3 * L];
        const float* bb = (const float*)d_in[3 + 3 * L];

        xx_kernel<<<(BATCH * NPTS + 255) / 256, 256, 0, stream>>>(xin, Cin, bstride, xx);
        gram_kernel<<<dim3(NPTS / TS, NPTS / TS, BATCH), 256, 0, stream>>>(xin, Cin, bstride, G);
        topk_kernel<<<BATCH * NPTS, 256, 0, stream>>>(G, xx, idx);
        if (Cout >= 128)
            pq_gemm_kernel<128><<<dim3(Cout / 128, NPTS / 64, BATCH), 256, 0, stream>>>(xin, Cin, bstride, W, Cout, p, q);
        else
            pq_gemm_kernel<64><<<dim3(Cout / 64, NPTS / 64, BATCH), 256, 0, stream>>>(xin, Cin, bstride, W, Cout, p, q);
        switch (Cout) {
            case 64:   stats_kernel<64>  <<<NBLK, 256, 0, stream>>>(p, q, idx, vmax, vmin, partials); break;
            case 128:  stats_kernel<128> <<<NBLK, 256, 0, stream>>>(p, q, idx, vmax, vmin, partials); break;
            case 256:  stats_kernel<256> <<<NBLK, 256, 0, stream>>>(p, q, idx, vmax, vmin, partials); break;
            case 512:  stats_kernel<512> <<<NBLK, 256, 0, stream>>>(p, q, idx, vmax, vmin, partials); break;
            case 1024: stats_kernel<1024><<<NBLK, 256, 0, stream>>>(p, q, idx, vmax, vmin, partials); break;
        }
        scaleshift_kernel<<<(Cout + 255) / 256, 256, 0, stream>>>(partials, g, bb, Cout, NBLK, sc);
        apply_kernel<<<dim3(Cout / 32, NPTS / 32, BATCH), 256, 0, stream>>>(vmax, vmin, sc, Cout, choff, feat);

        xin = feat + (size_t)choff * NPTS;
        bstride = (size_t)FEATC * NPTS;
    }

    pool_kernel<<<BATCH * FEATC, 256, 0, stream>>>(feat, pooled);
    final_kernel<<<512, 256, 0, stream>>>(pooled, Wm, bm, gm, betam, out);
}

// Round 5
// 1836.512 us; speedup vs baseline: 1.4173x; 1.0691x over previous
//
#include <hip/hip_runtime.h>
#include <math.h>

#define BATCH 4
#define NPTS 1024
#define KNN 20
#define EPS 1e-5f
#define FEATC 2048

// Workspace budget note (R4 post-mortem): total footprint kept under 67 MB.
// The R2-R4 layout used 99 MB; failure signature (first launch right, all
// replays identically wrong) indicts OOB ws writes corrupting the harness's
// pristine input copies. vmax/vmin (32 MB) eliminated via two-pass gather.

// ---------------- xx: per-point squared norm ----------------
__global__ void xx_kernel(const float* __restrict__ x, int Cin, size_t bstride,
                          float* __restrict__ xx) {
    int t = blockIdx.x * blockDim.x + threadIdx.x;  // b*NPTS + n
    if (t >= BATCH * NPTS) return;
    int b = t / NPTS, n = t % NPTS;
    const float* xb = x + (size_t)b * bstride;
    float s = 0.f;
    for (int c = 0; c < Cin; ++c) { float v = xb[(size_t)c * NPTS + n]; s += v * v; }
    xx[t] = s;
}

// ---------------- Gram matrix: G[b][n][m] = dot(x_n, x_m) ----------------
#define TS 64
#define KC 16
__global__ void gram_kernel(const float* __restrict__ x, int Cin, size_t bstride,
                            float* __restrict__ G) {
    // grid: (NPTS/TS, NPTS/TS, BATCH); block 256
    int b = blockIdx.z;
    int n0 = blockIdx.y * TS;
    int m0 = blockIdx.x * TS;
    const float* xb = x + (size_t)b * bstride;
    __shared__ float As[KC][TS];
    __shared__ float Bs[KC][TS];
    int tid = threadIdx.x;
    int tn = tid % 16, tm = tid / 16;  // 4x4 outputs per thread
    float acc[4][4] = {};
    for (int c0 = 0; c0 < Cin; c0 += KC) {
        for (int i = tid; i < KC * TS; i += 256) {
            int cc = i / TS, nn = i % TS;
            float av = 0.f, bv = 0.f;
            if (c0 + cc < Cin) {
                av = xb[(size_t)(c0 + cc) * NPTS + n0 + nn];
                bv = xb[(size_t)(c0 + cc) * NPTS + m0 + nn];
            }
            As[cc][nn] = av;
            Bs[cc][nn] = bv;
        }
        __syncthreads();
        for (int cc = 0; cc < KC; ++cc) {
            float a[4], bb[4];
#pragma unroll
            for (int i = 0; i < 4; i++) a[i] = As[cc][tn * 4 + i];
#pragma unroll
            for (int j = 0; j < 4; j++) bb[j] = Bs[cc][tm * 4 + j];
#pragma unroll
            for (int i = 0; i < 4; i++)
#pragma unroll
                for (int j = 0; j < 4; j++) acc[i][j] += a[i] * bb[j];
        }
        __syncthreads();
    }
    float* Gb = G + (size_t)b * NPTS * NPTS;
#pragma unroll
    for (int i = 0; i < 4; i++)
#pragma unroll
        for (int j = 0; j < 4; j++)
            Gb[(size_t)(n0 + tn * 4 + i) * NPTS + m0 + tm * 4 + j] = acc[i][j];
}

// ---------------- top-K selection per row ----------------
__global__ void topk_kernel(const float* __restrict__ G, const float* __restrict__ xx,
                            int* __restrict__ idx) {
    // grid BATCH*NPTS, block 256
    int t = blockIdx.x;
    int b = t / NPTS, n = t % NPTS;
    const float* Gr = G + (size_t)b * NPTS * NPTS + (size_t)n * NPTS;
    const float* xxb = xx + b * NPTS;
    __shared__ float dist[NPTS];
    __shared__ float rv[256];
    __shared__ int ri[256];
    int tid = threadIdx.x;
    float xxn = xxb[n];
    for (int m = tid; m < NPTS; m += 256)
        dist[m] = (2.f * Gr[m] - xxn) - xxb[m];  // matches ref op order
    __syncthreads();
    int* out = idx + (size_t)t * KNN;
    for (int k = 0; k < KNN; ++k) {
        float bv = -INFINITY; int bi = NPTS;
        for (int m = tid; m < NPTS; m += 256) {
            float v = dist[m];
            if (v > bv || (v == bv && m < bi)) { bv = v; bi = m; }
        }
        rv[tid] = bv; ri[tid] = bi;
        __syncthreads();
        for (int s = 128; s > 0; s >>= 1) {
            if (tid < s) {
                float v2 = rv[tid + s]; int i2 = ri[tid + s];
                if (v2 > rv[tid] || (v2 == rv[tid] && i2 < ri[tid])) { rv[tid] = v2; ri[tid] = i2; }
            }
            __syncthreads();
        }
        if (tid == 0) { out[k] = ri[0]; dist[ri[0]] = -INFINITY; }
        __syncthreads();
    }
}

// ---------------- p/q: tiled GEMM  p = W1*x, q = (W2-W1)*x ----------------
// grid: (Cout/TOUT, NPTS/64, BATCH); block 256 = 16 (o-groups) x 16 (n-groups)
// __launch_bounds__(256,2): cap 256 VGPR (2 waves/EU) — default heuristic chose
// 64 VGPR and spilled the 64-float accumulator array to scratch (R3: 472 MB
// WRITE_SIZE vs 33 MB of real output).
template <int TOUT>
__global__ __launch_bounds__(256, 2)
void pq_gemm_kernel(const float* __restrict__ x, int Cin, size_t bstride,
                    const float* __restrict__ W, int Cout,
                    float* __restrict__ p, float* __restrict__ q) {
    constexpr int RO = TOUT / 16;  // outputs per thread in o (4 or 8)
    int b = blockIdx.z;
    int o0 = blockIdx.x * TOUT;
    int n0 = blockIdx.y * 64;
    const float* xb = x + (size_t)b * bstride;
    __shared__ float W1s[KC][TOUT];
    __shared__ float WQs[KC][TOUT];
    __shared__ float Xs[KC][64];
    int tid = threadIdx.x;
    int tn = tid % 16;  // o group: o = o0 + tn*RO + i
    int tm = tid / 16;  // n group: n = n0 + tm*4 + j
    float accp[RO][4] = {};
    float accq[RO][4] = {};

    for (int c0 = 0; c0 < Cin; c0 += KC) {
        // ---- stage X chunk: KC x 64 floats, float4 per thread ----
        {
            int i = tid * 4;
            int cc = i >> 6, nn = i & 63;
            float4 v = make_float4(0.f, 0.f, 0.f, 0.f);
            if (c0 + cc < Cin)
                v = *(const float4*)(xb + (size_t)(c0 + cc) * NPTS + n0 + nn);
            *(float4*)(&Xs[cc][nn]) = v;
        }
        // ---- stage W chunk transposed: W1s/WQs[cc][row] ----
        {
            constexpr int PARTS = 256 / TOUT;        // 4 (TOUT=64) or 2 (TOUT=128)
            constexpr int CPW = KC / PARTS;          // cc per thread: 4 or 8
            int r = tid % TOUT;
            int cg = (tid / TOUT) * CPW;
            const float* Wr = W + (size_t)(o0 + r) * 2 * Cin;
#pragma unroll
            for (int u = 0; u < CPW; u += 4) {
                int cc = cg + u;
                float4 w1 = make_float4(0.f, 0.f, 0.f, 0.f);
                float4 w2 = make_float4(0.f, 0.f, 0.f, 0.f);
                if (c0 + cc < Cin) {
                    w1 = *(const float4*)(Wr + c0 + cc);
                    w2 = *(const float4*)(Wr + Cin + c0 + cc);
                }
                W1s[cc + 0][r] = w1.x; WQs[cc + 0][r] = w2.x - w1.x;
                W1s[cc + 1][r] = w1.y; WQs[cc + 1][r] = w2.y - w1.y;
                W1s[cc + 2][r] = w1.z; WQs[cc + 2][r] = w2.z - w1.z;
                W1s[cc + 3][r] = w1.w; WQs[cc + 3][r] = w2.w - w1.w;
            }
        }
        __syncthreads();
#pragma unroll
        for (int cc = 0; cc < KC; ++cc) {
            float4 xv = *(const float4*)(&Xs[cc][tm * 4]);
            float w1[RO], wq[RO];
#pragma unroll
            for (int g = 0; g < RO; g += 4) {
                float4 a = *(const float4*)(&W1s[cc][tn * RO + g]);
                w1[g + 0] = a.x; w1[g + 1] = a.y; w1[g + 2] = a.z; w1[g + 3] = a.w;
                float4 aq = *(const float4*)(&WQs[cc][tn * RO + g]);
                wq[g + 0] = aq.x; wq[g + 1] = aq.y; wq[g + 2] = aq.z; wq[g + 3] = aq.w;
            }
            float xj[4] = {xv.x, xv.y, xv.z, xv.w};
#pragma unroll
            for (int i = 0; i < RO; i++)
#pragma unroll
                for (int j = 0; j < 4; j++) {
                    accp[i][j] += w1[i] * xj[j];
                    accq[i][j] += wq[i] * xj[j];
                }
        }
        __syncthreads();
    }
    // ---- write out: for each of 4 n rows, RO consecutive o floats ----
#pragma unroll
    for (int j = 0; j < 4; j++) {
        int n = n0 + tm * 4 + j;
        size_t base = ((size_t)b * NPTS + n) * Cout + o0 + tn * RO;
#pragma unroll
        for (int g = 0; g < RO; g += 4) {
            float4 vp = make_float4(accp[g + 0][j], accp[g + 1][j], accp[g + 2][j], accp[g + 3][j]);
            float4 vq = make_float4(accq[g + 0][j], accq[g + 1][j], accq[g + 2][j], accq[g + 3][j]);
            *(float4*)(p + base + g) = vp;
            *(float4*)(q + base + g) = vq;
        }
    }
}

// ---------------- stats pass 1: BN sum/sumsq only (deterministic partials) ----------------
template <int COUT>
__global__ void stats_kernel(const float* __restrict__ p, const float* __restrict__ q,
                             const int* __restrict__ idx,
                             float* __restrict__ partials) {
    constexpr int CA = (COUT < 256) ? COUT : 256;
    constexpr int PP = 256 / CA;
    constexpr int CH = COUT / CA;
    constexpr int NCHUNK = 16;
    int bid = blockIdx.x;
    int b = bid / (NPTS / NCHUNK);
    int n0 = (bid % (NPTS / NCHUNK)) * NCHUNK;
    int c = threadIdx.x % CA;
    int sub = threadIdx.x / CA;
    float s[CH] = {}, ss[CH] = {};
    for (int nl = sub; nl < NCHUNK; nl += PP) {
        int n = n0 + nl;
        size_t nb = (size_t)b * NPTS + n;
        const int* ix = idx + nb * KNN;
        float qv[CH];
#pragma unroll
        for (int j = 0; j < CH; j++) qv[j] = q[nb * COUT + c + j * CA];
        for (int k = 0; k < KNN; ++k) {
            int m = ix[k];
            size_t pb = ((size_t)b * NPTS + m) * COUT + c;
#pragma unroll
            for (int j = 0; j < CH; j++) {
                float v = p[pb + j * CA] + qv[j];
                s[j] += v;
                ss[j] += v * v;
            }
        }
    }
    // deterministic block-level reduction over the PP sub-threads per channel
    __shared__ float red[256];
    float* outp = partials + (size_t)bid * 2 * COUT;
#pragma unroll
    for (int j = 0; j < CH; j++) {
        red[threadIdx.x] = s[j];
        __syncthreads();
        for (int st = PP / 2; st > 0; st >>= 1) {
            if (sub < st) red[threadIdx.x] += red[threadIdx.x + st * CA];
            __syncthreads();
        }
        if (sub == 0) outp[c + j * CA] = red[c];
        __syncthreads();
        red[threadIdx.x] = ss[j];
        __syncthreads();
        for (int st = PP / 2; st > 0; st >>= 1) {
            if (sub < st) red[threadIdx.x] += red[threadIdx.x + st * CA];
            __syncthreads();
        }
        if (sub == 0) outp[COUT + c + j * CA] = red[c];
        __syncthreads();
    }
}

// ---------------- BN scale/shift from partials (deterministic serial reduce) ----------------
__global__ void scaleshift_kernel(const float* __restrict__ partials, const float* __restrict__ g,
                                  const float* __restrict__ beta, int Cout, int nblk,
                                  float* __restrict__ sc) {
    int c = blockIdx.x * 256 + threadIdx.x;
    if (c >= Cout) return;
    float s0 = 0.f, s1 = 0.f;
    for (int b = 0; b < nblk; ++b) {
        s0 += partials[(size_t)b * 2 * Cout + c];
        s1 += partials[(size_t)b * 2 * Cout + Cout + c];
    }
    float cnt = (float)(BATCH * NPTS * KNN);
    float mean = s0 / cnt;
    float var = s1 / cnt - mean * mean;
    float s = g[c] * rsqrtf(var + EPS);
    sc[c] = s;
    sc[Cout + c] = beta[c] - mean * s;
}

// ---------------- pass 2: gather max/min, BN+leaky, transpose to (B, C, N) feat ----------------
__global__ void apply_kernel(const float* __restrict__ p, const float* __restrict__ q,
                             const int* __restrict__ idx, const float* __restrict__ sc,
                             int Cout, int choff, float* __restrict__ feat) {
    // grid: (Cout/32, NPTS/32, BATCH); block 256 = 32 (c) x 8 (n-sub)
    __shared__ float tile[32][33];
    __shared__ int nidx[32][KNN];
    int b = blockIdx.z;
    int c0 = blockIdx.x * 32, n0 = blockIdx.y * 32;
    int tx = threadIdx.x % 32, ty = threadIdx.x / 32;
    // stage neighbor indices for this n-tile: 32*20 ints
    for (int i = threadIdx.x; i < 32 * KNN; i += 256) {
        int nn = i / KNN, kk = i % KNN;
        nidx[nn][kk] = idx[((size_t)b * NPTS + n0 + nn) * KNN + kk];
    }
    __syncthreads();
    int c = c0 + tx;
    float s = sc[c], sh = sc[Cout + c];
    for (int i = ty; i < 32; i += 8) {
        int n = n0 + i;
        size_t nb = (size_t)b * NPTS + n;
        float qv = q[nb * Cout + c];
        float mx = -INFINITY, mn = INFINITY;
        for (int k = 0; k < KNN; ++k) {
            int m = nidx[i][k];
            float v = p[((size_t)b * NPTS + m) * Cout + c] + qv;
            mx = fmaxf(mx, v);
            mn = fminf(mn, v);
        }
        float v = (s >= 0.f) ? mx : mn;
        v = s * v + sh;
        tile[i][tx] = (v > 0.f) ? v : 0.2f * v;
    }
    __syncthreads();
    for (int i = ty; i < 32; i += 8) {
        feat[((size_t)b * FEATC + choff + c0 + i) * NPTS + n0 + tx] = tile[tx][i];
    }
}

// ---------------- pooling: max and mean over N ----------------
__global__ void pool_kernel(const float* __restrict__ feat, float* __restrict__ pooled) {
    // grid BATCH*FEATC, block 256
    int t = blockIdx.x;
    int b = t >> 11, c = t & (FEATC - 1);
    const float* row = feat + (size_t)t * NPTS;
    int tid = threadIdx.x;
    float mx = -INFINITY, sm = 0.f;
    for (int n = tid; n < NPTS; n += 256) { float v = row[n]; mx = fmaxf(mx, v); sm += v; }
    __shared__ float smx[256], ssm[256];
    smx[tid] = mx; ssm[tid] = sm;
    __syncthreads();
    for (int s = 128; s > 0; s >>= 1) {
        if (tid < s) { smx[tid] = fmaxf(smx[tid], smx[tid + s]); ssm[tid] += ssm[tid + s]; }
        __syncthreads();
    }
    if (tid == 0) {
        pooled[b * 4096 + c] = smx[0];
        pooled[b * 4096 + 2048 + c] = ssm[0] * (1.f / NPTS);
    }
}

// ---------------- final GEMV + batch-BN + leaky ----------------
__global__ void final_kernel(const float* __restrict__ pooled, const float* __restrict__ Wm,
                             const float* __restrict__ bm, const float* __restrict__ gm,
                             const float* __restrict__ betam, float* __restrict__ out) {
    // grid 512, block 256
    int o = blockIdx.x;
    int tid = threadIdx.x;
    float acc[BATCH] = {};
    for (int t = tid; t < 4096; t += 256) {
        float w = Wm[(size_t)o * 4096 + t];
#pragma unroll
        for (int b = 0; b < BATCH; b++) acc[b] += w * pooled[b * 4096 + t];
    }
    __shared__ float red[256];
    float zb[BATCH];
    for (int b = 0; b < BATCH; b++) {
        red[tid] = acc[b];
        __syncthreads();
        for (int s = 128; s > 0; s >>= 1) {
            if (tid < s) red[tid] += red[tid + s];
            __syncthreads();
        }
        zb[b] = red[0];
        __syncthreads();
    }
    if (tid == 0) {
        float z[BATCH];
        float mean = 0.f;
        for (int b = 0; b < BATCH; b++) { z[b] = zb[b] + bm[o]; mean += z[b]; }
        mean *= (1.f / BATCH);
        float var = 0.f;
        for (int b = 0; b < BATCH; b++) { float d = z[b] - mean; var += d * d; }
        var *= (1.f / BATCH);
        float s = gm[o] * rsqrtf(var + EPS);
        for (int b = 0; b < BATCH; b++) {
            float v = (z[b] - mean) * s + betam[o];
            out[b * 512 + o] = (v > 0.f) ? v : 0.2f * v;
        }
    }
}

extern "C" void kernel_launch(void* const* d_in, const int* in_sizes, int n_in,
                              void* d_out, int out_size, void* d_ws, size_t ws_size,
                              hipStream_t stream) {
    const float* x = (const float*)d_in[0];
    const float* Wm = (const float*)d_in[19];
    const float* bm = (const float*)d_in[20];
    const float* gm = (const float*)d_in[21];
    const float* betam = (const float*)d_in[22];
    float* out = (float*)d_out;

    char* ws = (char*)d_ws;
    // Compact layout — total 67 MB.
    float* G        = (float*)(ws);                                    // [0,16) MB (shared with p)
    float* p        = G;
    float* q        = (float*)(ws + (size_t)(16 << 20));               // [16,32) MB
    float* feat     = (float*)(ws + (size_t)(32 << 20));               // [32,64) MB
    int*   idx      = (int*)  (ws + (size_t)(64 << 20));               // 320 KB
    float* xx       = (float*)(ws + (size_t)(64 << 20) + (384 << 10)); // 16 KB
    float* sc       = (float*)(ws + (size_t)(64 << 20) + (448 << 10)); // 8 KB
    float* pooled   = (float*)(ws + (size_t)(64 << 20) + (512 << 10)); // 64 KB
    float* partials = (float*)(ws + (size_t)(65 << 20));               // [65,67) MB

    const int cins[6]   = {8, 64, 64, 128, 256, 512};
    const int couts[6]  = {64, 64, 128, 256, 512, 1024};
    const int choffs[6] = {0, 64, 128, 256, 512, 1024};

    const float* xin = x;
    size_t bstride = (size_t)8 * NPTS;
    const int NBLK = BATCH * (NPTS / 16);  // 256 stats blocks

    for (int L = 0; L < 6; ++L) {
        int Cin = cins[L], Cout = couts[L], choff = choffs[L];
        const float* W = (const float*)d_in[1 + 3 * L];
        const float* g = (const float*)d_in[2 + 3 * L];
        const float* bb = (const float*)d_in[3 + 3 * L];

        xx_kernel<<<(BATCH * NPTS + 255) / 256, 256, 0, stream>>>(xin, Cin, bstride, xx);
        gram_kernel<<<dim3(NPTS / TS, NPTS / TS, BATCH), 256, 0, stream>>>(xin, Cin, bstride, G);
        topk_kernel<<<BATCH * NPTS, 256, 0, stream>>>(G, xx, idx);
        if (Cout >= 128)
            pq_gemm_kernel<128><<<dim3(Cout / 128, NPTS / 64, BATCH), 256, 0, stream>>>(xin, Cin, bstride, W, Cout, p, q);
        else
            pq_gemm_kernel<64><<<dim3(Cout / 64, NPTS / 64, BATCH), 256, 0, stream>>>(xin, Cin, bstride, W, Cout, p, q);
        switch (Cout) {
            case 64:   stats_kernel<64>  <<<NBLK, 256, 0, stream>>>(p, q, idx, partials); break;
            case 128:  stats_kernel<128> <<<NBLK, 256, 0, stream>>>(p, q, idx, partials); break;
            case 256:  stats_kernel<256> <<<NBLK, 256, 0, stream>>>(p, q, idx, partials); break;
            case 512:  stats_kernel<512> <<<NBLK, 256, 0, stream>>>(p, q, idx, partials); break;
            case 1024: stats_kernel<1024><<<NBLK, 256, 0, stream>>>(p, q, idx, partials); break;
        }
        scaleshift_kernel<<<(Cout + 255) / 256, 256, 0, stream>>>(partials, g, bb, Cout, NBLK, sc);
        apply_kernel<<<dim3(Cout / 32, NPTS / 32, BATCH), 256, 0, stream>>>(p, q, idx, sc, Cout, choff, feat);

        xin = feat + (size_t)choff * NPTS;
        bstride = (size_t)FEATC * NPTS;
    }

    pool_kernel<<<BATCH * FEATC, 256, 0, stream>>>(feat, pooled);
    final_kernel<<<512, 256, 0, stream>>>(pooled, Wm, bm, gm, betam, out);
}

// Round 6
// 1796.814 us; speedup vs baseline: 1.4487x; 1.0221x over previous
//
#include <hip/hip_runtime.h>
#include <math.h>

#define BATCH 4
#define NPTS 1024
#define KNN 20
#define EPS 1e-5f
#define FEATC 2048

// Workspace budget note (R4 post-mortem): total footprint kept under 67 MB.
// 99 MB layout produced OOB ws writes corrupting harness pristine inputs
// (first launch right, all replays identically wrong).

// ---------------- xx: per-point squared norm ----------------
__global__ void xx_kernel(const float* __restrict__ x, int Cin, size_t bstride,
                          float* __restrict__ xx) {
    int t = blockIdx.x * blockDim.x + threadIdx.x;  // b*NPTS + n
    if (t >= BATCH * NPTS) return;
    int b = t / NPTS, n = t % NPTS;
    const float* xb = x + (size_t)b * bstride;
    float s = 0.f;
    for (int c = 0; c < Cin; ++c) { float v = xb[(size_t)c * NPTS + n]; s += v * v; }
    xx[t] = s;
}

// ---------------- Gram matrix: G[b][n][m] = dot(x_n, x_m) ----------------
// 64(n) x 128(m) tile, 4x8 per thread (R5: was 4x4 at 0.5 MAC/LDS-byte, 3x
// LDS-bound; 4x8 gives 0.67 MAC/B). launch_bounds prevents R3-style spill.
#define KC 16
__global__ __launch_bounds__(256, 2)
void gram_kernel(const float* __restrict__ x, int Cin, size_t bstride,
                 float* __restrict__ G) {
    // grid: (NPTS/128, NPTS/64, BATCH); block 256 = 16(tn) x 16(tm)
    int b = blockIdx.z;
    int n0 = blockIdx.y * 64;
    int m0 = blockIdx.x * 128;
    const float* xb = x + (size_t)b * bstride;
    __shared__ float As[KC][64];
    __shared__ float Bs[KC][128];
    int tid = threadIdx.x;
    int tn = tid % 16, tm = tid / 16;
    float acc[4][8] = {};
    for (int c0 = 0; c0 < Cin; c0 += KC) {
        // stage A: 16x64, one float4/thread
        {
            int i = tid * 4;
            int cc = i >> 6, nn = i & 63;
            float4 v = make_float4(0.f, 0.f, 0.f, 0.f);
            if (c0 + cc < Cin) v = *(const float4*)(xb + (size_t)(c0 + cc) * NPTS + n0 + nn);
            *(float4*)(&As[cc][nn]) = v;
        }
        // stage B: 16x128, two float4/thread
        {
            int i = tid * 8;
            int cc = i >> 7, mm = i & 127;
            float4 v0 = make_float4(0.f, 0.f, 0.f, 0.f);
            float4 v1 = make_float4(0.f, 0.f, 0.f, 0.f);
            if (c0 + cc < Cin) {
                const float* r = xb + (size_t)(c0 + cc) * NPTS + m0 + mm;
                v0 = *(const float4*)(r);
                v1 = *(const float4*)(r + 4);
            }
            *(float4*)(&Bs[cc][mm]) = v0;
            *(float4*)(&Bs[cc][mm + 4]) = v1;
        }
        __syncthreads();
#pragma unroll
        for (int cc = 0; cc < KC; ++cc) {
            float4 a4 = *(const float4*)(&As[cc][tn * 4]);
            float4 b0 = *(const float4*)(&Bs[cc][tm * 8]);
            float4 b1 = *(const float4*)(&Bs[cc][tm * 8 + 4]);
            float a[4] = {a4.x, a4.y, a4.z, a4.w};
            float bb[8] = {b0.x, b0.y, b0.z, b0.w, b1.x, b1.y, b1.z, b1.w};
#pragma unroll
            for (int i = 0; i < 4; i++)
#pragma unroll
                for (int j = 0; j < 8; j++) acc[i][j] += a[i] * bb[j];
        }
        __syncthreads();
    }
    float* Gb = G + (size_t)b * NPTS * NPTS;
#pragma unroll
    for (int i = 0; i < 4; i++) {
        size_t row = (size_t)(n0 + tn * 4 + i) * NPTS + m0 + tm * 8;
        *(float4*)(Gb + row)     = make_float4(acc[i][0], acc[i][1], acc[i][2], acc[i][3]);
        *(float4*)(Gb + row + 4) = make_float4(acc[i][4], acc[i][5], acc[i][6], acc[i][7]);
    }
}

// ---------------- top-K selection per row ----------------
__global__ void topk_kernel(const float* __restrict__ G, const float* __restrict__ xx,
                            int* __restrict__ idx) {
    // grid BATCH*NPTS, block 256
    int t = blockIdx.x;
    int b = t / NPTS, n = t % NPTS;
    const float* Gr = G + (size_t)b * NPTS * NPTS + (size_t)n * NPTS;
    const float* xxb = xx + b * NPTS;
    __shared__ float dist[NPTS];
    __shared__ float rv[256];
    __shared__ int ri[256];
    int tid = threadIdx.x;
    float xxn = xxb[n];
    {   // vectorized dist init: 256 threads x float4 = 1024
        float4 gv = ((const float4*)Gr)[tid];
        float4 xv = ((const float4*)xxb)[tid];
        float4 dv;
        dv.x = (2.f * gv.x - xxn) - xv.x;
        dv.y = (2.f * gv.y - xxn) - xv.y;
        dv.z = (2.f * gv.z - xxn) - xv.z;
        dv.w = (2.f * gv.w - xxn) - xv.w;
        ((float4*)dist)[tid] = dv;
    }
    __syncthreads();
    int* out = idx + (size_t)t * KNN;
    for (int k = 0; k < KNN; ++k) {
        float bv = -INFINITY; int bi = NPTS;
        for (int m = tid; m < NPTS; m += 256) {
            float v = dist[m];
            if (v > bv || (v == bv && m < bi)) { bv = v; bi = m; }
        }
        rv[tid] = bv; ri[tid] = bi;
        __syncthreads();
        for (int s = 128; s > 0; s >>= 1) {
            if (tid < s) {
                float v2 = rv[tid + s]; int i2 = ri[tid + s];
                if (v2 > rv[tid] || (v2 == rv[tid] && i2 < ri[tid])) { rv[tid] = v2; ri[tid] = i2; }
            }
            __syncthreads();
        }
        if (tid == 0) { out[k] = ri[0]; dist[ri[0]] = -INFINITY; }
        __syncthreads();
    }
}

// ---------------- p/q: tiled GEMM  p = W1*x, q = (W2-W1)*x ----------------
// grid: (Cout/TOUT, NPTS/64, BATCH); block 256 = 16 (o-groups) x 16 (n-groups)
// __launch_bounds__(256,2): R3 showed default heuristic spills accumulators.
// W staged in padded group-major layout [TOUT/8][KC*8+4] so the per-cc reads
// (lane stride was 8 floats -> 4-way bank conflict, R5: 1.7e7 conflicts)
// become 2-way max (free). Stride 132 floats => lane bank = (4*(o>>3)+(o&7))%32.
#define WSTRIDE (KC * 8 + 4)
template <int TOUT>
__global__ __launch_bounds__(256, 2)
void pq_gemm_kernel(const float* __restrict__ x, int Cin, size_t bstride,
                    const float* __restrict__ W, int Cout,
                    float* __restrict__ p, float* __restrict__ q) {
    constexpr int RO = TOUT / 16;  // outputs per thread in o (4 or 8)
    int b = blockIdx.z;
    int o0 = blockIdx.x * TOUT;
    int n0 = blockIdx.y * 64;
    const float* xb = x + (size_t)b * bstride;
    __shared__ float W1s[(TOUT / 8) * WSTRIDE];
    __shared__ float WQs[(TOUT / 8) * WSTRIDE];
    __shared__ float Xs[KC][64];
    int tid = threadIdx.x;
    int tn = tid % 16;  // o group: o = o0 + tn*RO + g
    int tm = tid / 16;  // n group: n = n0 + tm*4 + j
    float accp[RO][4] = {};
    float accq[RO][4] = {};
    const int rgrp = (tn * RO) >> 3;       // W-read group
    const int rrem = (tn * RO) & 7;        // offset within group

    for (int c0 = 0; c0 < Cin; c0 += KC) {
        // ---- stage X chunk: KC x 64 floats, float4 per thread ----
        {
            int i = tid * 4;
            int cc = i >> 6, nn = i & 63;
            float4 v = make_float4(0.f, 0.f, 0.f, 0.f);
            if (c0 + cc < Cin)
                v = *(const float4*)(xb + (size_t)(c0 + cc) * NPTS + n0 + nn);
            *(float4*)(&Xs[cc][nn]) = v;
        }
        // ---- stage W chunk, padded group-major ----
        {
            constexpr int PARTS = 256 / TOUT;        // 4 (TOUT=64) or 2 (TOUT=128)
            constexpr int CPW = KC / PARTS;          // cc per thread: 4 or 8
            int r = tid % TOUT;
            int cg = (tid / TOUT) * CPW;
            const float* Wr = W + (size_t)(o0 + r) * 2 * Cin;
            int wb = (r >> 3) * WSTRIDE + (r & 7);
#pragma unroll
            for (int u = 0; u < CPW; u += 4) {
                int cc = cg + u;
                float4 w1 = make_float4(0.f, 0.f, 0.f, 0.f);
                float4 w2 = make_float4(0.f, 0.f, 0.f, 0.f);
                if (c0 + cc < Cin) {
                    w1 = *(const float4*)(Wr + c0 + cc);
                    w2 = *(const float4*)(Wr + Cin + c0 + cc);
                }
                W1s[wb + (cc + 0) * 8] = w1.x; WQs[wb + (cc + 0) * 8] = w2.x - w1.x;
                W1s[wb + (cc + 1) * 8] = w1.y; WQs[wb + (cc + 1) * 8] = w2.y - w1.y;
                W1s[wb + (cc + 2) * 8] = w1.z; WQs[wb + (cc + 2) * 8] = w2.z - w1.z;
                W1s[wb + (cc + 3) * 8] = w1.w; WQs[wb + (cc + 3) * 8] = w2.w - w1.w;
            }
        }
        __syncthreads();
#pragma unroll
        for (int cc = 0; cc < KC; ++cc) {
            float4 xv = *(const float4*)(&Xs[cc][tm * 4]);
            float w1[RO], wq[RO];
#pragma unroll
            for (int g = 0; g < RO; g += 4) {
                float4 a = *(const float4*)(&W1s[rgrp * WSTRIDE + cc * 8 + rrem + g]);
                w1[g + 0] = a.x; w1[g + 1] = a.y; w1[g + 2] = a.z; w1[g + 3] = a.w;
                float4 aq = *(const float4*)(&WQs[rgrp * WSTRIDE + cc * 8 + rrem + g]);
                wq[g + 0] = aq.x; wq[g + 1] = aq.y; wq[g + 2] = aq.z; wq[g + 3] = aq.w;
            }
            float xj[4] = {xv.x, xv.y, xv.z, xv.w};
#pragma unroll
            for (int i = 0; i < RO; i++)
#pragma unroll
                for (int j = 0; j < 4; j++) {
                    accp[i][j] += w1[i] * xj[j];
                    accq[i][j] += wq[i] * xj[j];
                }
        }
        __syncthreads();
    }
    // ---- write out: for each of 4 n rows, RO consecutive o floats ----
#pragma unroll
    for (int j = 0; j < 4; j++) {
        int n = n0 + tm * 4 + j;
        size_t base = ((size_t)b * NPTS + n) * Cout + o0 + tn * RO;
#pragma unroll
        for (int g = 0; g < RO; g += 4) {
            float4 vp = make_float4(accp[g + 0][j], accp[g + 1][j], accp[g + 2][j], accp[g + 3][j]);
            float4 vq = make_float4(accq[g + 0][j], accq[g + 1][j], accq[g + 2][j], accq[g + 3][j]);
            *(float4*)(p + base + g) = vp;
            *(float4*)(q + base + g) = vq;
        }
    }
}

// ---------------- stats pass 1: BN sum/sumsq only (deterministic partials) ----------------
template <int COUT>
__global__ void stats_kernel(const float* __restrict__ p, const float* __restrict__ q,
                             const int* __restrict__ idx,
                             float* __restrict__ partials) {
    constexpr int CA = (COUT < 256) ? COUT : 256;
    constexpr int PP = 256 / CA;
    constexpr int CH = COUT / CA;
    constexpr int NCHUNK = 16;
    int bid = blockIdx.x;
    int b = bid / (NPTS / NCHUNK);
    int n0 = (bid % (NPTS / NCHUNK)) * NCHUNK;
    int c = threadIdx.x % CA;
    int sub = threadIdx.x / CA;
    float s[CH] = {}, ss[CH] = {};
    for (int nl = sub; nl < NCHUNK; nl += PP) {
        int n = n0 + nl;
        size_t nb = (size_t)b * NPTS + n;
        const int* ix = idx + nb * KNN;
        float qv[CH];
#pragma unroll
        for (int j = 0; j < CH; j++) qv[j] = q[nb * COUT + c + j * CA];
        for (int k = 0; k < KNN; ++k) {
            int m = ix[k];
            size_t pb = ((size_t)b * NPTS + m) * COUT + c;
#pragma unroll
            for (int j = 0; j < CH; j++) {
                float v = p[pb + j * CA] + qv[j];
                s[j] += v;
                ss[j] += v * v;
            }
        }
    }
    // deterministic block-level reduction over the PP sub-threads per channel
    __shared__ float red[256];
    float* outp = partials + (size_t)bid * 2 * COUT;
#pragma unroll
    for (int j = 0; j < CH; j++) {
        red[threadIdx.x] = s[j];
        __syncthreads();
        for (int st = PP / 2; st > 0; st >>= 1) {
            if (sub < st) red[threadIdx.x] += red[threadIdx.x + st * CA];
            __syncthreads();
        }
        if (sub == 0) outp[c + j * CA] = red[c];
        __syncthreads();
        red[threadIdx.x] = ss[j];
        __syncthreads();
        for (int st = PP / 2; st > 0; st >>= 1) {
            if (sub < st) red[threadIdx.x] += red[threadIdx.x + st * CA];
            __syncthreads();
        }
        if (sub == 0) outp[COUT + c + j * CA] = red[c];
        __syncthreads();
    }
}

// ---------------- BN scale/shift from partials (deterministic serial reduce) ----------------
__global__ void scaleshift_kernel(const float* __restrict__ partials, const float* __restrict__ g,
                                  const float* __restrict__ beta, int Cout, int nblk,
                                  float* __restrict__ sc) {
    int c = blockIdx.x * 256 + threadIdx.x;
    if (c >= Cout) return;
    float s0 = 0.f, s1 = 0.f;
    for (int b = 0; b < nblk; ++b) {
        s0 += partials[(size_t)b * 2 * Cout + c];
        s1 += partials[(size_t)b * 2 * Cout + Cout + c];
    }
    float cnt = (float)(BATCH * NPTS * KNN);
    float mean = s0 / cnt;
    float var = s1 / cnt - mean * mean;
    float s = g[c] * rsqrtf(var + EPS);
    sc[c] = s;
    sc[Cout + c] = beta[c] - mean * s;
}

// ---------------- pass 2: gather max/min, BN+leaky, transpose to (B, C, N) feat ----------------
__global__ void apply_kernel(const float* __restrict__ p, const float* __restrict__ q,
                             const int* __restrict__ idx, const float* __restrict__ sc,
                             int Cout, int choff, float* __restrict__ feat) {
    // grid: (Cout/32, NPTS/32, BATCH); block 256 = 32 (c) x 8 (n-sub)
    __shared__ float tile[32][33];
    __shared__ int nidx[32][KNN];
    int b = blockIdx.z;
    int c0 = blockIdx.x * 32, n0 = blockIdx.y * 32;
    int tx = threadIdx.x % 32, ty = threadIdx.x / 32;
    // stage neighbor indices for this n-tile: 32*20 ints
    for (int i = threadIdx.x; i < 32 * KNN; i += 256) {
        int nn = i / KNN, kk = i % KNN;
        nidx[nn][kk] = idx[((size_t)b * NPTS + n0 + nn) * KNN + kk];
    }
    __syncthreads();
    int c = c0 + tx;
    float s = sc[c], sh = sc[Cout + c];
    for (int i = ty; i < 32; i += 8) {
        int n = n0 + i;
        size_t nb = (size_t)b * NPTS + n;
        float qv = q[nb * Cout + c];
        float mx = -INFINITY, mn = INFINITY;
        for (int k = 0; k < KNN; ++k) {
            int m = nidx[i][k];
            float v = p[((size_t)b * NPTS + m) * Cout + c] + qv;
            mx = fmaxf(mx, v);
            mn = fminf(mn, v);
        }
        float v = (s >= 0.f) ? mx : mn;
        v = s * v + sh;
        tile[i][tx] = (v > 0.f) ? v : 0.2f * v;
    }
    __syncthreads();
    for (int i = ty; i < 32; i += 8) {
        feat[((size_t)b * FEATC + choff + c0 + i) * NPTS + n0 + tx] = tile[tx][i];
    }
}

// ---------------- pooling: max and mean over N ----------------
__global__ void pool_kernel(const float* __restrict__ feat, float* __restrict__ pooled) {
    // grid BATCH*FEATC, block 256
    int t = blockIdx.x;
    int b = t >> 11, c = t & (FEATC - 1);
    const float* row = feat + (size_t)t * NPTS;
    int tid = threadIdx.x;
    float mx = -INFINITY, sm = 0.f;
    for (int n = tid; n < NPTS; n += 256) { float v = row[n]; mx = fmaxf(mx, v); sm += v; }
    __shared__ float smx[256], ssm[256];
    smx[tid] = mx; ssm[tid] = sm;
    __syncthreads();
    for (int s = 128; s > 0; s >>= 1) {
        if (tid < s) { smx[tid] = fmaxf(smx[tid], smx[tid + s]); ssm[tid] += ssm[tid + s]; }
        __syncthreads();
    }
    if (tid == 0) {
        pooled[b * 4096 + c] = smx[0];
        pooled[b * 4096 + 2048 + c] = ssm[0] * (1.f / NPTS);
    }
}

// ---------------- final GEMV + batch-BN + leaky ----------------
__global__ void final_kernel(const float* __restrict__ pooled, const float* __restrict__ Wm,
                             const float* __restrict__ bm, const float* __restrict__ gm,
                             const float* __restrict__ betam, float* __restrict__ out) {
    // grid 512, block 256
    int o = blockIdx.x;
    int tid = threadIdx.x;
    float acc[BATCH] = {};
    for (int t = tid; t < 4096; t += 256) {
        float w = Wm[(size_t)o * 4096 + t];
#pragma unroll
        for (int b = 0; b < BATCH; b++) acc[b] += w * pooled[b * 4096 + t];
    }
    __shared__ float red[256];
    float zb[BATCH];
    for (int b = 0; b < BATCH; b++) {
        red[tid] = acc[b];
        __syncthreads();
        for (int s = 128; s > 0; s >>= 1) {
            if (tid < s) red[tid] += red[tid + s];
            __syncthreads();
        }
        zb[b] = red[0];
        __syncthreads();
    }
    if (tid == 0) {
        float z[BATCH];
        float mean = 0.f;
        for (int b = 0; b < BATCH; b++) { z[b] = zb[b] + bm[o]; mean += z[b]; }
        mean *= (1.f / BATCH);
        float var = 0.f;
        for (int b = 0; b < BATCH; b++) { float d = z[b] - mean; var += d * d; }
        var *= (1.f / BATCH);
        float s = gm[o] * rsqrtf(var + EPS);
        for (int b = 0; b < BATCH; b++) {
            float v = (z[b] - mean) * s + betam[o];
            out[b * 512 + o] = (v > 0.f) ? v : 0.2f * v;
        }
    }
}

extern "C" void kernel_launch(void* const* d_in, const int* in_sizes, int n_in,
                              void* d_out, int out_size, void* d_ws, size_t ws_size,
                              hipStream_t stream) {
    const float* x = (const float*)d_in[0];
    const float* Wm = (const float*)d_in[19];
    const float* bm = (const float*)d_in[20];
    const float* gm = (const float*)d_in[21];
    const float* betam = (const float*)d_in[22];
    float* out = (float*)d_out;

    char* ws = (char*)d_ws;
    // Compact layout — total 67 MB.
    float* G        = (float*)(ws);                                    // [0,16) MB (shared with p)
    float* p        = G;
    float* q        = (float*)(ws + (size_t)(16 << 20));               // [16,32) MB
    float* feat     = (float*)(ws + (size_t)(32 << 20));               // [32,64) MB
    int*   idx      = (int*)  (ws + (size_t)(64 << 20));               // 320 KB
    float* xx       = (float*)(ws + (size_t)(64 << 20) + (384 << 10)); // 16 KB
    float* sc       = (float*)(ws + (size_t)(64 << 20) + (448 << 10)); // 8 KB
    float* pooled   = (float*)(ws + (size_t)(64 << 20) + (512 << 10)); // 64 KB
    float* partials = (float*)(ws + (size_t)(65 << 20));               // [65,67) MB

    const int cins[6]   = {8, 64, 64, 128, 256, 512};
    const int couts[6]  = {64, 64, 128, 256, 512, 1024};
    const int choffs[6] = {0, 64, 128, 256, 512, 1024};

    const float* xin = x;
    size_t bstride = (size_t)8 * NPTS;
    const int NBLK = BATCH * (NPTS / 16);  // 256 stats blocks

    for (int L = 0; L < 6; ++L) {
        int Cin = cins[L], Cout = couts[L], choff = choffs[L];
        const float* W = (const float*)d_in[1 + 3 * L];
        const float* g = (const float*)d_in[2 + 3 * L];
        const float* bb = (const float*)d_in[3 + 3 * L];

        xx_kernel<<<(BATCH * NPTS + 255) / 256, 256, 0, stream>>>(xin, Cin, bstride, xx);
        gram_kernel<<<dim3(NPTS / 128, NPTS / 64, BATCH), 256, 0, stream>>>(xin, Cin, bstride, G);
        topk_kernel<<<BATCH * NPTS, 256, 0, stream>>>(G, xx, idx);
        if (Cout >= 128)
            pq_gemm_kernel<128><<<dim3(Cout / 128, NPTS / 64, BATCH), 256, 0, stream>>>(xin, Cin, bstride, W, Cout, p, q);
        else
            pq_gemm_kernel<64><<<dim3(Cout / 64, NPTS / 64, BATCH), 256, 0, stream>>>(xin, Cin, bstride, W, Cout, p, q);
        switch (Cout) {
            case 64:   stats_kernel<64>  <<<NBLK, 256, 0, stream>>>(p, q, idx, partials); break;
            case 128:  stats_kernel<128> <<<NBLK, 256, 0, stream>>>(p, q, idx, partials); break;
            case 256:  stats_kernel<256> <<<NBLK, 256, 0, stream>>>(p, q, idx, partials); break;
            case 512:  stats_kernel<512> <<<NBLK, 256, 0, stream>>>(p, q, idx, partials); break;
            case 1024: stats_kernel<1024><<<NBLK, 256, 0, stream>>>(p, q, idx, partials); break;
        }
        scaleshift_kernel<<<(Cout + 255) / 256, 256, 0, stream>>>(partials, g, bb, Cout, NBLK, sc);
        apply_kernel<<<dim3(Cout / 32, NPTS / 32, BATCH), 256, 0, stream>>>(p, q, idx, sc, Cout, choff, feat);

        xin = feat + (size_t)choff * NPTS;
        bstride = (size_t)FEATC * NPTS;
    }

    pool_kernel<<<BATCH * FEATC, 256, 0, stream>>>(feat, pooled);
    final_kernel<<<512, 256, 0, stream>>>(pooled, Wm, bm, gm, betam, out);
}

// Round 7
// 1476.483 us; speedup vs baseline: 1.7629x; 1.2170x over previous
//
#include <hip/hip_runtime.h>
#include <math.h>

#define BATCH 4
#define NPTS 1024
#define KNN 20
#define EPS 1e-5f
#define FEATC 2048

// Workspace budget note (R4 post-mortem): total footprint kept under 67 MB.
// 99 MB layout produced OOB ws writes corrupting harness pristine inputs
// (first launch right, all replays identically wrong).

// ---------------- xx: per-point squared norm ----------------
__global__ void xx_kernel(const float* __restrict__ x, int Cin, size_t bstride,
                          float* __restrict__ xx) {
    int t = blockIdx.x * blockDim.x + threadIdx.x;  // b*NPTS + n
    if (t >= BATCH * NPTS) return;
    int b = t / NPTS, n = t % NPTS;
    const float* xb = x + (size_t)b * bstride;
    float s = 0.f;
    for (int c = 0; c < Cin; ++c) { float v = xb[(size_t)c * NPTS + n]; s += v * v; }
    xx[t] = s;
}

// ---------------- Gram matrix: G[b][n][m] = dot(x_n, x_m) ----------------
// 64(n) x 128(m) tile, 4x8 per thread. launch_bounds prevents R3-style spill.
#define KC 16
__global__ __launch_bounds__(256, 2)
void gram_kernel(const float* __restrict__ x, int Cin, size_t bstride,
                 float* __restrict__ G) {
    // grid: (NPTS/128, NPTS/64, BATCH); block 256 = 16(tn) x 16(tm)
    int b = blockIdx.z;
    int n0 = blockIdx.y * 64;
    int m0 = blockIdx.x * 128;
    const float* xb = x + (size_t)b * bstride;
    __shared__ float As[KC][64];
    __shared__ float Bs[KC][128];
    int tid = threadIdx.x;
    int tn = tid % 16, tm = tid / 16;
    float acc[4][8] = {};
    for (int c0 = 0; c0 < Cin; c0 += KC) {
        // stage A: 16x64, one float4/thread
        {
            int i = tid * 4;
            int cc = i >> 6, nn = i & 63;
            float4 v = make_float4(0.f, 0.f, 0.f, 0.f);
            if (c0 + cc < Cin) v = *(const float4*)(xb + (size_t)(c0 + cc) * NPTS + n0 + nn);
            *(float4*)(&As[cc][nn]) = v;
        }
        // stage B: 16x128, two float4/thread
        {
            int i = tid * 8;
            int cc = i >> 7, mm = i & 127;
            float4 v0 = make_float4(0.f, 0.f, 0.f, 0.f);
            float4 v1 = make_float4(0.f, 0.f, 0.f, 0.f);
            if (c0 + cc < Cin) {
                const float* r = xb + (size_t)(c0 + cc) * NPTS + m0 + mm;
                v0 = *(const float4*)(r);
                v1 = *(const float4*)(r + 4);
            }
            *(float4*)(&Bs[cc][mm]) = v0;
            *(float4*)(&Bs[cc][mm + 4]) = v1;
        }
        __syncthreads();
#pragma unroll
        for (int cc = 0; cc < KC; ++cc) {
            float4 a4 = *(const float4*)(&As[cc][tn * 4]);
            float4 b0 = *(const float4*)(&Bs[cc][tm * 8]);
            float4 b1 = *(const float4*)(&Bs[cc][tm * 8 + 4]);
            float a[4] = {a4.x, a4.y, a4.z, a4.w};
            float bb[8] = {b0.x, b0.y, b0.z, b0.w, b1.x, b1.y, b1.z, b1.w};
#pragma unroll
            for (int i = 0; i < 4; i++)
#pragma unroll
                for (int j = 0; j < 8; j++) acc[i][j] += a[i] * bb[j];
        }
        __syncthreads();
    }
    float* Gb = G + (size_t)b * NPTS * NPTS;
#pragma unroll
    for (int i = 0; i < 4; i++) {
        size_t row = (size_t)(n0 + tn * 4 + i) * NPTS + m0 + tm * 8;
        *(float4*)(Gb + row)     = make_float4(acc[i][0], acc[i][1], acc[i][2], acc[i][3]);
        *(float4*)(Gb + row + 4) = make_float4(acc[i][4], acc[i][5], acc[i][6], acc[i][7]);
    }
}

// ---------------- top-K: one wave per row, barrier-free (R6 rewrite) ----------------
// Old version: 20 selection rounds x 9 __syncthreads = 180 barriers/block.
// New: dist in 16 regs/lane; per-k = unrolled local argmax + 6-level shfl_xor
// butterfly (value desc, lower-index tie-break = JAX top_k) + unrolled clear
// (no dynamic reg indexing -> no scratch). Block 256 = 4 independent waves.
__global__ __launch_bounds__(256)
void topk_kernel(const float* __restrict__ G, const float* __restrict__ xx,
                 int* __restrict__ idx) {
    // grid BATCH*NPTS/4
    int wid = threadIdx.x >> 6, lane = threadIdx.x & 63;
    int t = blockIdx.x * 4 + wid;
    int b = t >> 10, n = t & (NPTS - 1);
    const float* Gr = G + ((size_t)b * NPTS + n) * NPTS;
    const float* xxb = xx + b * NPTS;
    float xxn = xxb[n];
    float d[16];
    int base = lane * 4;
#pragma unroll
    for (int c = 0; c < 4; ++c) {
        float4 gv = *(const float4*)(Gr + c * 256 + base);
        float4 xv = *(const float4*)(xxb + c * 256 + base);
        d[c * 4 + 0] = (2.f * gv.x - xxn) - xv.x;
        d[c * 4 + 1] = (2.f * gv.y - xxn) - xv.y;
        d[c * 4 + 2] = (2.f * gv.z - xxn) - xv.z;
        d[c * 4 + 3] = (2.f * gv.w - xxn) - xv.w;
    }
    int* out = idx + (size_t)t * KNN;
    for (int k = 0; k < KNN; ++k) {
        // local argmax; slot order is index order, strict > keeps lowest index on tie
        float bv = d[0]; int bs = 0;
#pragma unroll
        for (int s = 1; s < 16; ++s)
            if (d[s] > bv) { bv = d[s]; bs = s; }
        int bm = ((bs >> 2) << 8) + base + (bs & 3);
#pragma unroll
        for (int off = 32; off >= 1; off >>= 1) {
            float ov = __shfl_xor(bv, off);
            int om = __shfl_xor(bm, off);
            if (ov > bv || (ov == bv && om < bm)) { bv = ov; bm = om; }
        }
        if (lane == 0) out[k] = bm;
        int rel = bm - base;
#pragma unroll
        for (int s = 0; s < 16; ++s)
            if (rel == (((s >> 2) << 8) | (s & 3))) d[s] = -INFINITY;
    }
}

// ---------------- p/q: tiled GEMM  p = W1*x, q = (W2-W1)*x ----------------
// grid: (Cout/TOUT, NPTS/64, BATCH); block 256 = 16 (o-groups) x 16 (n-groups)
// __launch_bounds__(256,2): R3 showed default heuristic spills accumulators.
// W staged padded group-major [TOUT/8][KC*8+4]: R5's 4-way conflict (1.7e7)
// -> 2.1e6 (R6 counters).
#define WSTRIDE (KC * 8 + 4)
template <int TOUT>
__global__ __launch_bounds__(256, 2)
void pq_gemm_kernel(const float* __restrict__ x, int Cin, size_t bstride,
                    const float* __restrict__ W, int Cout,
                    float* __restrict__ p, float* __restrict__ q) {
    constexpr int RO = TOUT / 16;  // outputs per thread in o (4 or 8)
    int b = blockIdx.z;
    int o0 = blockIdx.x * TOUT;
    int n0 = blockIdx.y * 64;
    const float* xb = x + (size_t)b * bstride;
    __shared__ float W1s[(TOUT / 8) * WSTRIDE];
    __shared__ float WQs[(TOUT / 8) * WSTRIDE];
    __shared__ float Xs[KC][64];
    int tid = threadIdx.x;
    int tn = tid % 16;  // o group: o = o0 + tn*RO + g
    int tm = tid / 16;  // n group: n = n0 + tm*4 + j
    float accp[RO][4] = {};
    float accq[RO][4] = {};
    const int rgrp = (tn * RO) >> 3;       // W-read group
    const int rrem = (tn * RO) & 7;        // offset within group

    for (int c0 = 0; c0 < Cin; c0 += KC) {
        // ---- stage X chunk: KC x 64 floats, float4 per thread ----
        {
            int i = tid * 4;
            int cc = i >> 6, nn = i & 63;
            float4 v = make_float4(0.f, 0.f, 0.f, 0.f);
            if (c0 + cc < Cin)
                v = *(const float4*)(xb + (size_t)(c0 + cc) * NPTS + n0 + nn);
            *(float4*)(&Xs[cc][nn]) = v;
        }
        // ---- stage W chunk, padded group-major ----
        {
            constexpr int PARTS = 256 / TOUT;        // 4 (TOUT=64) or 2 (TOUT=128)
            constexpr int CPW = KC / PARTS;          // cc per thread: 4 or 8
            int r = tid % TOUT;
            int cg = (tid / TOUT) * CPW;
            const float* Wr = W + (size_t)(o0 + r) * 2 * Cin;
            int wb = (r >> 3) * WSTRIDE + (r & 7);
#pragma unroll
            for (int u = 0; u < CPW; u += 4) {
                int cc = cg + u;
                float4 w1 = make_float4(0.f, 0.f, 0.f, 0.f);
                float4 w2 = make_float4(0.f, 0.f, 0.f, 0.f);
                if (c0 + cc < Cin) {
                    w1 = *(const float4*)(Wr + c0 + cc);
                    w2 = *(const float4*)(Wr + Cin + c0 + cc);
                }
                W1s[wb + (cc + 0) * 8] = w1.x; WQs[wb + (cc + 0) * 8] = w2.x - w1.x;
                W1s[wb + (cc + 1) * 8] = w1.y; WQs[wb + (cc + 1) * 8] = w2.y - w1.y;
                W1s[wb + (cc + 2) * 8] = w1.z; WQs[wb + (cc + 2) * 8] = w2.z - w1.z;
                W1s[wb + (cc + 3) * 8] = w1.w; WQs[wb + (cc + 3) * 8] = w2.w - w1.w;
            }
        }
        __syncthreads();
#pragma unroll
        for (int cc = 0; cc < KC; ++cc) {
            float4 xv = *(const float4*)(&Xs[cc][tm * 4]);
            float w1[RO], wq[RO];
#pragma unroll
            for (int g = 0; g < RO; g += 4) {
                float4 a = *(const float4*)(&W1s[rgrp * WSTRIDE + cc * 8 + rrem + g]);
                w1[g + 0] = a.x; w1[g + 1] = a.y; w1[g + 2] = a.z; w1[g + 3] = a.w;
                float4 aq = *(const float4*)(&WQs[rgrp * WSTRIDE + cc * 8 + rrem + g]);
                wq[g + 0] = aq.x; wq[g + 1] = aq.y; wq[g + 2] = aq.z; wq[g + 3] = aq.w;
            }
            float xj[4] = {xv.x, xv.y, xv.z, xv.w};
#pragma unroll
            for (int i = 0; i < RO; i++)
#pragma unroll
                for (int j = 0; j < 4; j++) {
                    accp[i][j] += w1[i] * xj[j];
                    accq[i][j] += wq[i] * xj[j];
                }
        }
        __syncthreads();
    }
    // ---- write out: for each of 4 n rows, RO consecutive o floats ----
#pragma unroll
    for (int j = 0; j < 4; j++) {
        int n = n0 + tm * 4 + j;
        size_t base = ((size_t)b * NPTS + n) * Cout + o0 + tn * RO;
#pragma unroll
        for (int g = 0; g < RO; g += 4) {
            float4 vp = make_float4(accp[g + 0][j], accp[g + 1][j], accp[g + 2][j], accp[g + 3][j]);
            float4 vq = make_float4(accq[g + 0][j], accq[g + 1][j], accq[g + 2][j], accq[g + 3][j]);
            *(float4*)(p + base + g) = vp;
            *(float4*)(q + base + g) = vq;
        }
    }
}

// ---------------- stats pass 1: BN sum/sumsq (deterministic partials) ----------------
// R6: channel chunks parallelized over blockIdx.y (was serial CH loop ->
// 1 block/CU at L6). Each block covers a CA<=256 channel slice of 16 points.
template <int COUT>
__global__ void stats_kernel(const float* __restrict__ p, const float* __restrict__ q,
                             const int* __restrict__ idx,
                             float* __restrict__ partials) {
    constexpr int CA = (COUT < 256) ? COUT : 256;
    constexpr int PP = 256 / CA;
    constexpr int NCH = COUT / CA;
    constexpr int NCHUNK = 16;
    int bid = blockIdx.x;
    int b = bid / (NPTS / NCHUNK);
    int n0 = (bid % (NPTS / NCHUNK)) * NCHUNK;
    int cl = threadIdx.x % CA;
    int c = blockIdx.y * CA + cl;
    int sub = threadIdx.x / CA;
    float s = 0.f, ss = 0.f;
    for (int nl = sub; nl < NCHUNK; nl += PP) {
        int n = n0 + nl;
        size_t nb = (size_t)b * NPTS + n;
        const int* ix = idx + nb * KNN;
        float qv = q[nb * COUT + c];
        for (int k = 0; k < KNN; ++k) {
            int m = ix[k];
            float v = p[((size_t)b * NPTS + m) * COUT + c] + qv;
            s += v;
            ss += v * v;
        }
    }
    // deterministic block-level reduction over the PP sub-threads per channel
    __shared__ float red[256];
    float* outp = partials + ((size_t)bid * NCH + blockIdx.y) * 2 * CA;
    red[threadIdx.x] = s;
    __syncthreads();
    for (int st = PP / 2; st > 0; st >>= 1) {
        if (sub < st) red[threadIdx.x] += red[threadIdx.x + st * CA];
        __syncthreads();
    }
    if (sub == 0) outp[cl] = red[cl];
    __syncthreads();
    red[threadIdx.x] = ss;
    __syncthreads();
    for (int st = PP / 2; st > 0; st >>= 1) {
        if (sub < st) red[threadIdx.x] += red[threadIdx.x + st * CA];
        __syncthreads();
    }
    if (sub == 0) outp[CA + cl] = red[cl];
}

// ---------------- BN scale/shift from partials (deterministic serial reduce) ----------------
__global__ void scaleshift_kernel(const float* __restrict__ partials, const float* __restrict__ g,
                                  const float* __restrict__ beta, int Cout, int nblk,
                                  int CA, int NCH, float* __restrict__ sc) {
    int c = blockIdx.x * 256 + threadIdx.x;
    if (c >= Cout) return;
    int chunk = c / CA, within = c % CA;
    float s0 = 0.f, s1 = 0.f;
    for (int b = 0; b < nblk; ++b) {
        const float* pp = partials + ((size_t)b * NCH + chunk) * 2 * CA;
        s0 += pp[within];
        s1 += pp[CA + within];
    }
    float cnt = (float)(BATCH * NPTS * KNN);
    float mean = s0 / cnt;
    float var = s1 / cnt - mean * mean;
    float s = g[c] * rsqrtf(var + EPS);
    sc[c] = s;
    sc[Cout + c] = beta[c] - mean * s;
}

// ---------------- pass 2: gather max/min, BN+leaky, transpose to (B, C, N) feat ----------------
__global__ void apply_kernel(const float* __restrict__ p, const float* __restrict__ q,
                             const int* __restrict__ idx, const float* __restrict__ sc,
                             int Cout, int choff, float* __restrict__ feat) {
    // grid: (Cout/32, NPTS/32, BATCH); block 256 = 32 (c) x 8 (n-sub)
    __shared__ float tile[32][33];
    __shared__ int nidx[32][KNN];
    int b = blockIdx.z;
    int c0 = blockIdx.x * 32, n0 = blockIdx.y * 32;
    int tx = threadIdx.x % 32, ty = threadIdx.x / 32;
    // stage neighbor indices for this n-tile: 32*20 ints
    for (int i = threadIdx.x; i < 32 * KNN; i += 256) {
        int nn = i / KNN, kk = i % KNN;
        nidx[nn][kk] = idx[((size_t)b * NPTS + n0 + nn) * KNN + kk];
    }
    __syncthreads();
    int c = c0 + tx;
    float s = sc[c], sh = sc[Cout + c];
    for (int i = ty; i < 32; i += 8) {
        int n = n0 + i;
        size_t nb = (size_t)b * NPTS + n;
        float qv = q[nb * Cout + c];
        float mx = -INFINITY, mn = INFINITY;
        for (int k = 0; k < KNN; ++k) {
            int m = nidx[i][k];
            float v = p[((size_t)b * NPTS + m) * Cout + c] + qv;
            mx = fmaxf(mx, v);
            mn = fminf(mn, v);
        }
        float v = (s >= 0.f) ? mx : mn;
        v = s * v + sh;
        tile[i][tx] = (v > 0.f) ? v : 0.2f * v;
    }
    __syncthreads();
    for (int i = ty; i < 32; i += 8) {
        feat[((size_t)b * FEATC + choff + c0 + i) * NPTS + n0 + tx] = tile[tx][i];
    }
}

// ---------------- pooling: max and mean over N ----------------
__global__ void pool_kernel(const float* __restrict__ feat, float* __restrict__ pooled) {
    // grid BATCH*FEATC, block 256
    int t = blockIdx.x;
    int b = t >> 11, c = t & (FEATC - 1);
    const float* row = feat + (size_t)t * NPTS;
    int tid = threadIdx.x;
    float mx = -INFINITY, sm = 0.f;
    for (int n = tid; n < NPTS; n += 256) { float v = row[n]; mx = fmaxf(mx, v); sm += v; }
    __shared__ float smx[256], ssm[256];
    smx[tid] = mx; ssm[tid] = sm;
    __syncthreads();
    for (int s = 128; s > 0; s >>= 1) {
        if (tid < s) { smx[tid] = fmaxf(smx[tid], smx[tid + s]); ssm[tid] += ssm[tid + s]; }
        __syncthreads();
    }
    if (tid == 0) {
        pooled[b * 4096 + c] = smx[0];
        pooled[b * 4096 + 2048 + c] = ssm[0] * (1.f / NPTS);
    }
}

// ---------------- final GEMV + batch-BN + leaky ----------------
__global__ void final_kernel(const float* __restrict__ pooled, const float* __restrict__ Wm,
                             const float* __restrict__ bm, const float* __restrict__ gm,
                             const float* __restrict__ betam, float* __restrict__ out) {
    // grid 512, block 256
    int o = blockIdx.x;
    int tid = threadIdx.x;
    float acc[BATCH] = {};
    for (int t = tid; t < 4096; t += 256) {
        float w = Wm[(size_t)o * 4096 + t];
#pragma unroll
        for (int b = 0; b < BATCH; b++) acc[b] += w * pooled[b * 4096 + t];
    }
    __shared__ float red[256];
    float zb[BATCH];
    for (int b = 0; b < BATCH; b++) {
        red[tid] = acc[b];
        __syncthreads();
        for (int s = 128; s > 0; s >>= 1) {
            if (tid < s) red[tid] += red[tid + s];
            __syncthreads();
        }
        zb[b] = red[0];
        __syncthreads();
    }
    if (tid == 0) {
        float z[BATCH];
        float mean = 0.f;
        for (int b = 0; b < BATCH; b++) { z[b] = zb[b] + bm[o]; mean += z[b]; }
        mean *= (1.f / BATCH);
        float var = 0.f;
        for (int b = 0; b < BATCH; b++) { float d = z[b] - mean; var += d * d; }
        var *= (1.f / BATCH);
        float s = gm[o] * rsqrtf(var + EPS);
        for (int b = 0; b < BATCH; b++) {
            float v = (z[b] - mean) * s + betam[o];
            out[b * 512 + o] = (v > 0.f) ? v : 0.2f * v;
        }
    }
}

extern "C" void kernel_launch(void* const* d_in, const int* in_sizes, int n_in,
                              void* d_out, int out_size, void* d_ws, size_t ws_size,
                              hipStream_t stream) {
    const float* x = (const float*)d_in[0];
    const float* Wm = (const float*)d_in[19];
    const float* bm = (const float*)d_in[20];
    const float* gm = (const float*)d_in[21];
    const float* betam = (const float*)d_in[22];
    float* out = (float*)d_out;

    char* ws = (char*)d_ws;
    // Compact layout — total 67 MB.
    float* G        = (float*)(ws);                                    // [0,16) MB (shared with p)
    float* p        = G;
    float* q        = (float*)(ws + (size_t)(16 << 20));               // [16,32) MB
    float* feat     = (float*)(ws + (size_t)(32 << 20));               // [32,64) MB
    int*   idx      = (int*)  (ws + (size_t)(64 << 20));               // 320 KB
    float* xx       = (float*)(ws + (size_t)(64 << 20) + (384 << 10)); // 16 KB
    float* sc       = (float*)(ws + (size_t)(64 << 20) + (448 << 10)); // 8 KB
    float* pooled   = (float*)(ws + (size_t)(64 << 20) + (512 << 10)); // 64 KB
    float* partials = (float*)(ws + (size_t)(65 << 20));               // [65,67) MB

    const int cins[6]   = {8, 64, 64, 128, 256, 512};
    const int couts[6]  = {64, 64, 128, 256, 512, 1024};
    const int choffs[6] = {0, 64, 128, 256, 512, 1024};

    const float* xin = x;
    size_t bstride = (size_t)8 * NPTS;
    const int NBLK = BATCH * (NPTS / 16);  // 256 n-chunk blocks for stats

    for (int L = 0; L < 6; ++L) {
        int Cin = cins[L], Cout = couts[L], choff = choffs[L];
        const float* W = (const float*)d_in[1 + 3 * L];
        const float* g = (const float*)d_in[2 + 3 * L];
        const float* bb = (const float*)d_in[3 + 3 * L];

        xx_kernel<<<(BATCH * NPTS + 255) / 256, 256, 0, stream>>>(xin, Cin, bstride, xx);
        gram_kernel<<<dim3(NPTS / 128, NPTS / 64, BATCH), 256, 0, stream>>>(xin, Cin, bstride, G);
        topk_kernel<<<BATCH * NPTS / 4, 256, 0, stream>>>(G, xx, idx);
        if (Cout >= 128)
            pq_gemm_kernel<128><<<dim3(Cout / 128, NPTS / 64, BATCH), 256, 0, stream>>>(xin, Cin, bstride, W, Cout, p, q);
        else
            pq_gemm_kernel<64><<<dim3(Cout / 64, NPTS / 64, BATCH), 256, 0, stream>>>(xin, Cin, bstride, W, Cout, p, q);
        int CA = (Cout < 256) ? Cout : 256;
        int NCH = Cout / CA;
        switch (Cout) {
            case 64:   stats_kernel<64>  <<<dim3(NBLK, 1), 256, 0, stream>>>(p, q, idx, partials); break;
            case 128:  stats_kernel<128> <<<dim3(NBLK, 1), 256, 0, stream>>>(p, q, idx, partials); break;
            case 256:  stats_kernel<256> <<<dim3(NBLK, 1), 256, 0, stream>>>(p, q, idx, partials); break;
            case 512:  stats_kernel<512> <<<dim3(NBLK, 2), 256, 0, stream>>>(p, q, idx, partials); break;
            case 1024: stats_kernel<1024><<<dim3(NBLK, 4), 256, 0, stream>>>(p, q, idx, partials); break;
        }
        scaleshift_kernel<<<(Cout + 255) / 256, 256, 0, stream>>>(partials, g, bb, Cout, NBLK, CA, NCH, sc);
        apply_kernel<<<dim3(Cout / 32, NPTS / 32, BATCH), 256, 0, stream>>>(p, q, idx, sc, Cout, choff, feat);

        xin = feat + (size_t)choff * NPTS;
        bstride = (size_t)FEATC * NPTS;
    }

    pool_kernel<<<BATCH * FEATC, 256, 0, stream>>>(feat, pooled);
    final_kernel<<<512, 256, 0, stream>>>(pooled, Wm, bm, gm, betam, out);
}

// Round 8
// 1421.263 us; speedup vs baseline: 1.8314x; 1.0389x over previous
//
#include <hip/hip_runtime.h>
#include <math.h>

#define BATCH 4
#define NPTS 1024
#define KNN 20
#define EPS 1e-5f
#define FEATC 2048

// Workspace budget note (R4 post-mortem): total footprint kept under 67 MB.
// 99 MB layout produced OOB ws writes corrupting harness pristine inputs
// (first launch right, all replays identically wrong).

// ---------------- xx: per-point squared norm ----------------
__global__ void xx_kernel(const float* __restrict__ x, int Cin, size_t bstride,
                          float* __restrict__ xx) {
    int t = blockIdx.x * blockDim.x + threadIdx.x;  // b*NPTS + n
    if (t >= BATCH * NPTS) return;
    int b = t / NPTS, n = t % NPTS;
    const float* xb = x + (size_t)b * bstride;
    float s = 0.f;
    for (int c = 0; c < Cin; ++c) { float v = xb[(size_t)c * NPTS + n]; s += v * v; }
    xx[t] = s;
}

// ---------------- Gram matrix: G[b][n][m] = dot(x_n, x_m) ----------------
// 64(n) x 128(m) tile, 4x8 per thread. R7: register-prefetch double-buffer —
// next chunk's global loads issue right after the barrier and are consumed
// (LDS store) only at the top of the next iteration, hiding load latency
// behind the 16-cc compute.
#define KC 16
__global__ __launch_bounds__(256, 2)
void gram_kernel(const float* __restrict__ x, int Cin, size_t bstride,
                 float* __restrict__ G) {
    // grid: (NPTS/128, NPTS/64, BATCH); block 256 = 16(tn) x 16(tm)
    int b = blockIdx.z;
    int n0 = blockIdx.y * 64;
    int m0 = blockIdx.x * 128;
    const float* xb = x + (size_t)b * bstride;
    __shared__ float As[KC][64];
    __shared__ float Bs[KC][128];
    int tid = threadIdx.x;
    int tn = tid % 16, tm = tid / 16;
    float acc[4][8] = {};

    const int ia = tid * 4, cca = ia >> 6, nna = ia & 63;
    const int ib = tid * 8, ccb = ib >> 7, mmb = ib & 127;
    float4 pa, pb0, pb1;
    auto prefetch = [&](int c0) {
        pa = make_float4(0.f, 0.f, 0.f, 0.f);
        pb0 = make_float4(0.f, 0.f, 0.f, 0.f);
        pb1 = make_float4(0.f, 0.f, 0.f, 0.f);
        if (c0 + cca < Cin) pa = *(const float4*)(xb + (size_t)(c0 + cca) * NPTS + n0 + nna);
        if (c0 + ccb < Cin) {
            const float* r = xb + (size_t)(c0 + ccb) * NPTS + m0 + mmb;
            pb0 = *(const float4*)(r);
            pb1 = *(const float4*)(r + 4);
        }
    };
    prefetch(0);
    for (int c0 = 0; c0 < Cin; c0 += KC) {
        *(float4*)(&As[cca][nna]) = pa;
        *(float4*)(&Bs[ccb][mmb]) = pb0;
        *(float4*)(&Bs[ccb][mmb + 4]) = pb1;
        __syncthreads();
        if (c0 + KC < Cin) prefetch(c0 + KC);
#pragma unroll
        for (int cc = 0; cc < KC; ++cc) {
            float4 a4 = *(const float4*)(&As[cc][tn * 4]);
            float4 b0 = *(const float4*)(&Bs[cc][tm * 8]);
            float4 b1 = *(const float4*)(&Bs[cc][tm * 8 + 4]);
            float a[4] = {a4.x, a4.y, a4.z, a4.w};
            float bb[8] = {b0.x, b0.y, b0.z, b0.w, b1.x, b1.y, b1.z, b1.w};
#pragma unroll
            for (int i = 0; i < 4; i++)
#pragma unroll
                for (int j = 0; j < 8; j++) acc[i][j] += a[i] * bb[j];
        }
        __syncthreads();
    }
    float* Gb = G + (size_t)b * NPTS * NPTS;
#pragma unroll
    for (int i = 0; i < 4; i++) {
        size_t row = (size_t)(n0 + tn * 4 + i) * NPTS + m0 + tm * 8;
        *(float4*)(Gb + row)     = make_float4(acc[i][0], acc[i][1], acc[i][2], acc[i][3]);
        *(float4*)(Gb + row + 4) = make_float4(acc[i][4], acc[i][5], acc[i][6], acc[i][7]);
    }
}

// ---------------- top-K: one wave per row, barrier-free (R6 rewrite) ----------------
__global__ __launch_bounds__(256)
void topk_kernel(const float* __restrict__ G, const float* __restrict__ xx,
                 int* __restrict__ idx) {
    // grid BATCH*NPTS/4
    int wid = threadIdx.x >> 6, lane = threadIdx.x & 63;
    int t = blockIdx.x * 4 + wid;
    int b = t >> 10, n = t & (NPTS - 1);
    const float* Gr = G + ((size_t)b * NPTS + n) * NPTS;
    const float* xxb = xx + b * NPTS;
    float xxn = xxb[n];
    float d[16];
    int base = lane * 4;
#pragma unroll
    for (int c = 0; c < 4; ++c) {
        float4 gv = *(const float4*)(Gr + c * 256 + base);
        float4 xv = *(const float4*)(xxb + c * 256 + base);
        d[c * 4 + 0] = (2.f * gv.x - xxn) - xv.x;
        d[c * 4 + 1] = (2.f * gv.y - xxn) - xv.y;
        d[c * 4 + 2] = (2.f * gv.z - xxn) - xv.z;
        d[c * 4 + 3] = (2.f * gv.w - xxn) - xv.w;
    }
    int* out = idx + (size_t)t * KNN;
    for (int k = 0; k < KNN; ++k) {
        float bv = d[0]; int bs = 0;
#pragma unroll
        for (int s = 1; s < 16; ++s)
            if (d[s] > bv) { bv = d[s]; bs = s; }
        int bm = ((bs >> 2) << 8) + base + (bs & 3);
#pragma unroll
        for (int off = 32; off >= 1; off >>= 1) {
            float ov = __shfl_xor(bv, off);
            int om = __shfl_xor(bm, off);
            if (ov > bv || (ov == bv && om < bm)) { bv = ov; bm = om; }
        }
        if (lane == 0) out[k] = bm;
        int rel = bm - base;
#pragma unroll
        for (int s = 0; s < 16; ++s)
            if (rel == (((s >> 2) << 8) | (s & 3))) d[s] = -INFINITY;
    }
}

// ---------------- p/q: tiled GEMM  p = W1*x, q = (W2-W1)*x ----------------
// R7 restructure: TOUT=64 for ALL layers (L6 grid 512->1024 blocks: R6 showed
// occupancy was grid-limited at 2 blocks/CU) + register-prefetch double-buffer.
// RO=4 => plain [KC][64] W staging is conflict-free (lane stride 4 floats:
// 16 lanes span all 32 banks 2-way; the R5 4-way was stride-8 with RO=8).
__global__ __launch_bounds__(256, 2)
void pq_gemm_kernel(const float* __restrict__ x, int Cin, size_t bstride,
                    const float* __restrict__ W, int Cout,
                    float* __restrict__ p, float* __restrict__ q) {
    // grid: (Cout/64, NPTS/64, BATCH); block 256 = 16(tn:o) x 16(tm:n)
    int b = blockIdx.z;
    int o0 = blockIdx.x * 64;
    int n0 = blockIdx.y * 64;
    const float* xb = x + (size_t)b * bstride;
    __shared__ float W1s[KC][64];
    __shared__ float WQs[KC][64];
    __shared__ float Xs[KC][64];
    int tid = threadIdx.x;
    int tn = tid % 16;  // o = o0 + tn*4 + i
    int tm = tid / 16;  // n = n0 + tm*4 + j
    float accp[4][4] = {};
    float accq[4][4] = {};

    const int ix = tid * 4, ccx = ix >> 6, nnx = ix & 63;
    const int r = tid % 64, cg = (tid / 64) * 4;   // W row, cc-group of 4
    const float* Wr = W + (size_t)(o0 + r) * 2 * Cin;
    float4 px, pw1, pw2;
    auto prefetch = [&](int c0) {
        px = make_float4(0.f, 0.f, 0.f, 0.f);
        pw1 = make_float4(0.f, 0.f, 0.f, 0.f);
        pw2 = make_float4(0.f, 0.f, 0.f, 0.f);
        if (c0 + ccx < Cin) px = *(const float4*)(xb + (size_t)(c0 + ccx) * NPTS + n0 + nnx);
        if (c0 + cg < Cin) {   // all Cin are multiples of 4
            pw1 = *(const float4*)(Wr + c0 + cg);
            pw2 = *(const float4*)(Wr + Cin + c0 + cg);
        }
    };
    prefetch(0);
    for (int c0 = 0; c0 < Cin; c0 += KC) {
        *(float4*)(&Xs[ccx][nnx]) = px;
        W1s[cg + 0][r] = pw1.x; WQs[cg + 0][r] = pw2.x - pw1.x;
        W1s[cg + 1][r] = pw1.y; WQs[cg + 1][r] = pw2.y - pw1.y;
        W1s[cg + 2][r] = pw1.z; WQs[cg + 2][r] = pw2.z - pw1.z;
        W1s[cg + 3][r] = pw1.w; WQs[cg + 3][r] = pw2.w - pw1.w;
        __syncthreads();
        if (c0 + KC < Cin) prefetch(c0 + KC);
#pragma unroll
        for (int cc = 0; cc < KC; ++cc) {
            float4 wv = *(const float4*)(&W1s[cc][tn * 4]);
            float4 qv = *(const float4*)(&WQs[cc][tn * 4]);
            float4 xv = *(const float4*)(&Xs[cc][tm * 4]);
            float w1[4] = {wv.x, wv.y, wv.z, wv.w};
            float wq[4] = {qv.x, qv.y, qv.z, qv.w};
            float xj[4] = {xv.x, xv.y, xv.z, xv.w};
#pragma unroll
            for (int i = 0; i < 4; i++)
#pragma unroll
                for (int j = 0; j < 4; j++) {
                    accp[i][j] += w1[i] * xj[j];
                    accq[i][j] += wq[i] * xj[j];
                }
        }
        __syncthreads();
    }
    // ---- write out: for each of 4 n rows, 4 consecutive o floats ----
#pragma unroll
    for (int j = 0; j < 4; j++) {
        int n = n0 + tm * 4 + j;
        size_t base = ((size_t)b * NPTS + n) * Cout + o0 + tn * 4;
        *(float4*)(p + base) = make_float4(accp[0][j], accp[1][j], accp[2][j], accp[3][j]);
        *(float4*)(q + base) = make_float4(accq[0][j], accq[1][j], accq[2][j], accq[3][j]);
    }
}

// ---------------- stats pass 1: BN sum/sumsq (deterministic partials) ----------------
template <int COUT>
__global__ void stats_kernel(const float* __restrict__ p, const float* __restrict__ q,
                             const int* __restrict__ idx,
                             float* __restrict__ partials) {
    constexpr int CA = (COUT < 256) ? COUT : 256;
    constexpr int PP = 256 / CA;
    constexpr int NCH = COUT / CA;
    constexpr int NCHUNK = 16;
    int bid = blockIdx.x;
    int b = bid / (NPTS / NCHUNK);
    int n0 = (bid % (NPTS / NCHUNK)) * NCHUNK;
    int cl = threadIdx.x % CA;
    int c = blockIdx.y * CA + cl;
    int sub = threadIdx.x / CA;
    float s = 0.f, ss = 0.f;
    for (int nl = sub; nl < NCHUNK; nl += PP) {
        int n = n0 + nl;
        size_t nb = (size_t)b * NPTS + n;
        const int* ix = idx + nb * KNN;
        float qv = q[nb * COUT + c];
        for (int k = 0; k < KNN; ++k) {
            int m = ix[k];
            float v = p[((size_t)b * NPTS + m) * COUT + c] + qv;
            s += v;
            ss += v * v;
        }
    }
    __shared__ float red[256];
    float* outp = partials + ((size_t)bid * NCH + blockIdx.y) * 2 * CA;
    red[threadIdx.x] = s;
    __syncthreads();
    for (int st = PP / 2; st > 0; st >>= 1) {
        if (sub < st) red[threadIdx.x] += red[threadIdx.x + st * CA];
        __syncthreads();
    }
    if (sub == 0) outp[cl] = red[cl];
    __syncthreads();
    red[threadIdx.x] = ss;
    __syncthreads();
    for (int st = PP / 2; st > 0; st >>= 1) {
        if (sub < st) red[threadIdx.x] += red[threadIdx.x + st * CA];
        __syncthreads();
    }
    if (sub == 0) outp[CA + cl] = red[cl];
}

// ---------------- BN scale/shift from partials (deterministic serial reduce) ----------------
__global__ void scaleshift_kernel(const float* __restrict__ partials, const float* __restrict__ g,
                                  const float* __restrict__ beta, int Cout, int nblk,
                                  int CA, int NCH, float* __restrict__ sc) {
    int c = blockIdx.x * 256 + threadIdx.x;
    if (c >= Cout) return;
    int chunk = c / CA, within = c % CA;
    float s0 = 0.f, s1 = 0.f;
    for (int b = 0; b < nblk; ++b) {
        const float* pp = partials + ((size_t)b * NCH + chunk) * 2 * CA;
        s0 += pp[within];
        s1 += pp[CA + within];
    }
    float cnt = (float)(BATCH * NPTS * KNN);
    float mean = s0 / cnt;
    float var = s1 / cnt - mean * mean;
    float s = g[c] * rsqrtf(var + EPS);
    sc[c] = s;
    sc[Cout + c] = beta[c] - mean * s;
}

// ---------------- pass 2: gather max/min, BN+leaky, transpose to (B, C, N) feat ----------------
__global__ void apply_kernel(const float* __restrict__ p, const float* __restrict__ q,
                             const int* __restrict__ idx, const float* __restrict__ sc,
                             int Cout, int choff, float* __restrict__ feat) {
    // grid: (Cout/32, NPTS/32, BATCH); block 256 = 32 (c) x 8 (n-sub)
    __shared__ float tile[32][33];
    __shared__ int nidx[32][KNN];
    int b = blockIdx.z;
    int c0 = blockIdx.x * 32, n0 = blockIdx.y * 32;
    int tx = threadIdx.x % 32, ty = threadIdx.x / 32;
    for (int i = threadIdx.x; i < 32 * KNN; i += 256) {
        int nn = i / KNN, kk = i % KNN;
        nidx[nn][kk] = idx[((size_t)b * NPTS + n0 + nn) * KNN + kk];
    }
    __syncthreads();
    int c = c0 + tx;
    float s = sc[c], sh = sc[Cout + c];
    for (int i = ty; i < 32; i += 8) {
        int n = n0 + i;
        size_t nb = (size_t)b * NPTS + n;
        float qv = q[nb * Cout + c];
        float mx = -INFINITY, mn = INFINITY;
        for (int k = 0; k < KNN; ++k) {
            int m = nidx[i][k];
            float v = p[((size_t)b * NPTS + m) * Cout + c] + qv;
            mx = fmaxf(mx, v);
            mn = fminf(mn, v);
        }
        float v = (s >= 0.f) ? mx : mn;
        v = s * v + sh;
        tile[i][tx] = (v > 0.f) ? v : 0.2f * v;
    }
    __syncthreads();
    for (int i = ty; i < 32; i += 8) {
        feat[((size_t)b * FEATC + choff + c0 + i) * NPTS + n0 + tx] = tile[tx][i];
    }
}

// ---------------- pooling: max and mean over N ----------------
__global__ void pool_kernel(const float* __restrict__ feat, float* __restrict__ pooled) {
    // grid BATCH*FEATC, block 256
    int t = blockIdx.x;
    int b = t >> 11, c = t & (FEATC - 1);
    const float* row = feat + (size_t)t * NPTS;
    int tid = threadIdx.x;
    float mx = -INFINITY, sm = 0.f;
    for (int n = tid; n < NPTS; n += 256) { float v = row[n]; mx = fmaxf(mx, v); sm += v; }
    __shared__ float smx[256], ssm[256];
    smx[tid] = mx; ssm[tid] = sm;
    __syncthreads();
    for (int s = 128; s > 0; s >>= 1) {
        if (tid < s) { smx[tid] = fmaxf(smx[tid], smx[tid + s]); ssm[tid] += ssm[tid + s]; }
        __syncthreads();
    }
    if (tid == 0) {
        pooled[b * 4096 + c] = smx[0];
        pooled[b * 4096 + 2048 + c] = ssm[0] * (1.f / NPTS);
    }
}

// ---------------- final GEMV + batch-BN + leaky ----------------
__global__ void final_kernel(const float* __restrict__ pooled, const float* __restrict__ Wm,
                             const float* __restrict__ bm, const float* __restrict__ gm,
                             const float* __restrict__ betam, float* __restrict__ out) {
    // grid 512, block 256
    int o = blockIdx.x;
    int tid = threadIdx.x;
    float acc[BATCH] = {};
    for (int t = tid; t < 4096; t += 256) {
        float w = Wm[(size_t)o * 4096 + t];
#pragma unroll
        for (int b = 0; b < BATCH; b++) acc[b] += w * pooled[b * 4096 + t];
    }
    __shared__ float red[256];
    float zb[BATCH];
    for (int b = 0; b < BATCH; b++) {
        red[tid] = acc[b];
        __syncthreads();
        for (int s = 128; s > 0; s >>= 1) {
            if (tid < s) red[tid] += red[tid + s];
            __syncthreads();
        }
        zb[b] = red[0];
        __syncthreads();
    }
    if (tid == 0) {
        float z[BATCH];
        float mean = 0.f;
        for (int b = 0; b < BATCH; b++) { z[b] = zb[b] + bm[o]; mean += z[b]; }
        mean *= (1.f / BATCH);
        float var = 0.f;
        for (int b = 0; b < BATCH; b++) { float d = z[b] - mean; var += d * d; }
        var *= (1.f / BATCH);
        float s = gm[o] * rsqrtf(var + EPS);
        for (int b = 0; b < BATCH; b++) {
            float v = (z[b] - mean) * s + betam[o];
            out[b * 512 + o] = (v > 0.f) ? v : 0.2f * v;
        }
    }
}

extern "C" void kernel_launch(void* const* d_in, const int* in_sizes, int n_in,
                              void* d_out, int out_size, void* d_ws, size_t ws_size,
                              hipStream_t stream) {
    const float* x = (const float*)d_in[0];
    const float* Wm = (const float*)d_in[19];
    const float* bm = (const float*)d_in[20];
    const float* gm = (const float*)d_in[21];
    const float* betam = (const float*)d_in[22];
    float* out = (float*)d_out;

    char* ws = (char*)d_ws;
    // Compact layout — total 67 MB.
    float* G        = (float*)(ws);                                    // [0,16) MB (shared with p)
    float* p        = G;
    float* q        = (float*)(ws + (size_t)(16 << 20));               // [16,32) MB
    float* feat     = (float*)(ws + (size_t)(32 << 20));               // [32,64) MB
    int*   idx      = (int*)  (ws + (size_t)(64 << 20));               // 320 KB
    float* xx       = (float*)(ws + (size_t)(64 << 20) + (384 << 10)); // 16 KB
    float* sc       = (float*)(ws + (size_t)(64 << 20) + (448 << 10)); // 8 KB
    float* pooled   = (float*)(ws + (size_t)(64 << 20) + (512 << 10)); // 64 KB
    float* partials = (float*)(ws + (size_t)(65 << 20));               // [65,67) MB

    const int cins[6]   = {8, 64, 64, 128, 256, 512};
    const int couts[6]  = {64, 64, 128, 256, 512, 1024};
    const int choffs[6] = {0, 64, 128, 256, 512, 1024};

    const float* xin = x;
    size_t bstride = (size_t)8 * NPTS;
    const int NBLK = BATCH * (NPTS / 16);  // 256 n-chunk blocks for stats

    for (int L = 0; L < 6; ++L) {
        int Cin = cins[L], Cout = couts[L], choff = choffs[L];
        const float* W = (const float*)d_in[1 + 3 * L];
        const float* g = (const float*)d_in[2 + 3 * L];
        const float* bb = (const float*)d_in[3 + 3 * L];

        xx_kernel<<<(BATCH * NPTS + 255) / 256, 256, 0, stream>>>(xin, Cin, bstride, xx);
        gram_kernel<<<dim3(NPTS / 128, NPTS / 64, BATCH), 256, 0, stream>>>(xin, Cin, bstride, G);
        topk_kernel<<<BATCH * NPTS / 4, 256, 0, stream>>>(G, xx, idx);
        pq_gemm_kernel<<<dim3(Cout / 64, NPTS / 64, BATCH), 256, 0, stream>>>(xin, Cin, bstride, W, Cout, p, q);
        int CA = (Cout < 256) ? Cout : 256;
        int NCH = Cout / CA;
        switch (Cout) {
            case 64:   stats_kernel<64>  <<<dim3(NBLK, 1), 256, 0, stream>>>(p, q, idx, partials); break;
            case 128:  stats_kernel<128> <<<dim3(NBLK, 1), 256, 0, stream>>>(p, q, idx, partials); break;
            case 256:  stats_kernel<256> <<<dim3(NBLK, 1), 256, 0, stream>>>(p, q, idx, partials); break;
            case 512:  stats_kernel<512> <<<dim3(NBLK, 2), 256, 0, stream>>>(p, q, idx, partials); break;
            case 1024: stats_kernel<1024><<<dim3(NBLK, 4), 256, 0, stream>>>(p, q, idx, partials); break;
        }
        scaleshift_kernel<<<(Cout + 255) / 256, 256, 0, stream>>>(partials, g, bb, Cout, NBLK, CA, NCH, sc);
        apply_kernel<<<dim3(Cout / 32, NPTS / 32, BATCH), 256, 0, stream>>>(p, q, idx, sc, Cout, choff, feat);

        xin = feat + (size_t)choff * NPTS;
        bstride = (size_t)FEATC * NPTS;
    }

    pool_kernel<<<BATCH * FEATC, 256, 0, stream>>>(feat, pooled);
    final_kernel<<<512, 256, 0, stream>>>(pooled, Wm, bm, gm, betam, out);
}

// Round 9
// 1159.248 us; speedup vs baseline: 2.2454x; 1.2260x over previous
//
#include <hip/hip_runtime.h>
#include <math.h>

#define BATCH 4
#define NPTS 1024
#define KNN 20
#define EPS 1e-5f
#define FEATC 2048

// Workspace budget note (R4 post-mortem): total footprint kept under 67 MB.
// 99 MB layout produced OOB ws writes corrupting harness pristine inputs
// (first launch right, all replays identically wrong).
//
// R8: xx_kernel deleted — it was 6x ~124 us of pure latency (16 blocks,
// VALUBusy 0.08%). xx[b][n] == G[b][n][n] bitwise (same ascending-c FMA
// order), extracted by diag_kernel (~3 us) after gram.

// ---------------- Gram matrix: G[b][n][m] = dot(x_n, x_m) ----------------
// 64(n) x 128(m) tile, 4x8 per thread. R7: register-prefetch double-buffer —
// next chunk's global loads issue right after the barrier and are consumed
// (LDS store) only at the top of the next iteration, hiding load latency
// behind the 16-cc compute.
#define KC 16
__global__ __launch_bounds__(256, 2)
void gram_kernel(const float* __restrict__ x, int Cin, size_t bstride,
                 float* __restrict__ G) {
    // grid: (NPTS/128, NPTS/64, BATCH); block 256 = 16(tn) x 16(tm)
    int b = blockIdx.z;
    int n0 = blockIdx.y * 64;
    int m0 = blockIdx.x * 128;
    const float* xb = x + (size_t)b * bstride;
    __shared__ float As[KC][64];
    __shared__ float Bs[KC][128];
    int tid = threadIdx.x;
    int tn = tid % 16, tm = tid / 16;
    float acc[4][8] = {};

    const int ia = tid * 4, cca = ia >> 6, nna = ia & 63;
    const int ib = tid * 8, ccb = ib >> 7, mmb = ib & 127;
    float4 pa, pb0, pb1;
    auto prefetch = [&](int c0) {
        pa = make_float4(0.f, 0.f, 0.f, 0.f);
        pb0 = make_float4(0.f, 0.f, 0.f, 0.f);
        pb1 = make_float4(0.f, 0.f, 0.f, 0.f);
        if (c0 + cca < Cin) pa = *(const float4*)(xb + (size_t)(c0 + cca) * NPTS + n0 + nna);
        if (c0 + ccb < Cin) {
            const float* r = xb + (size_t)(c0 + ccb) * NPTS + m0 + mmb;
            pb0 = *(const float4*)(r);
            pb1 = *(const float4*)(r + 4);
        }
    };
    prefetch(0);
    for (int c0 = 0; c0 < Cin; c0 += KC) {
        *(float4*)(&As[cca][nna]) = pa;
        *(float4*)(&Bs[ccb][mmb]) = pb0;
        *(float4*)(&Bs[ccb][mmb + 4]) = pb1;
        __syncthreads();
        if (c0 + KC < Cin) prefetch(c0 + KC);
#pragma unroll
        for (int cc = 0; cc < KC; ++cc) {
            float4 a4 = *(const float4*)(&As[cc][tn * 4]);
            float4 b0 = *(const float4*)(&Bs[cc][tm * 8]);
            float4 b1 = *(const float4*)(&Bs[cc][tm * 8 + 4]);
            float a[4] = {a4.x, a4.y, a4.z, a4.w};
            float bb[8] = {b0.x, b0.y, b0.z, b0.w, b1.x, b1.y, b1.z, b1.w};
#pragma unroll
            for (int i = 0; i < 4; i++)
#pragma unroll
                for (int j = 0; j < 8; j++) acc[i][j] += a[i] * bb[j];
        }
        __syncthreads();
    }
    float* Gb = G + (size_t)b * NPTS * NPTS;
#pragma unroll
    for (int i = 0; i < 4; i++) {
        size_t row = (size_t)(n0 + tn * 4 + i) * NPTS + m0 + tm * 8;
        *(float4*)(Gb + row)     = make_float4(acc[i][0], acc[i][1], acc[i][2], acc[i][3]);
        *(float4*)(Gb + row + 4) = make_float4(acc[i][4], acc[i][5], acc[i][6], acc[i][7]);
    }
}

// ---------------- diag: xx[b][n] = G[b][n][n] (R8, replaces xx_kernel) ----------------
__global__ void diag_kernel(const float* __restrict__ G, float* __restrict__ xx) {
    int t = blockIdx.x * 256 + threadIdx.x;       // b*NPTS + n
    int b = t >> 10, n = t & (NPTS - 1);
    xx[t] = G[((size_t)b << 20) + (size_t)n * (NPTS + 1)];
}

// ---------------- top-K: one wave per row, barrier-free (R6 rewrite) ----------------
__global__ __launch_bounds__(256)
void topk_kernel(const float* __restrict__ G, const float* __restrict__ xx,
                 int* __restrict__ idx) {
    // grid BATCH*NPTS/4
    int wid = threadIdx.x >> 6, lane = threadIdx.x & 63;
    int t = blockIdx.x * 4 + wid;
    int b = t >> 10, n = t & (NPTS - 1);
    const float* Gr = G + ((size_t)b * NPTS + n) * NPTS;
    const float* xxb = xx + b * NPTS;
    float xxn = xxb[n];
    float d[16];
    int base = lane * 4;
#pragma unroll
    for (int c = 0; c < 4; ++c) {
        float4 gv = *(const float4*)(Gr + c * 256 + base);
        float4 xv = *(const float4*)(xxb + c * 256 + base);
        d[c * 4 + 0] = (2.f * gv.x - xxn) - xv.x;
        d[c * 4 + 1] = (2.f * gv.y - xxn) - xv.y;
        d[c * 4 + 2] = (2.f * gv.z - xxn) - xv.z;
        d[c * 4 + 3] = (2.f * gv.w - xxn) - xv.w;
    }
    int* out = idx + (size_t)t * KNN;
    for (int k = 0; k < KNN; ++k) {
        float bv = d[0]; int bs = 0;
#pragma unroll
        for (int s = 1; s < 16; ++s)
            if (d[s] > bv) { bv = d[s]; bs = s; }
        int bm = ((bs >> 2) << 8) + base + (bs & 3);
#pragma unroll
        for (int off = 32; off >= 1; off >>= 1) {
            float ov = __shfl_xor(bv, off);
            int om = __shfl_xor(bm, off);
            if (ov > bv || (ov == bv && om < bm)) { bv = ov; bm = om; }
        }
        if (lane == 0) out[k] = bm;
        int rel = bm - base;
#pragma unroll
        for (int s = 0; s < 16; ++s)
            if (rel == (((s >> 2) << 8) | (s & 3))) d[s] = -INFINITY;
    }
}

// ---------------- p/q: tiled GEMM  p = W1*x, q = (W2-W1)*x ----------------
// R7 restructure: TOUT=64 for ALL layers (L6 grid 512->1024 blocks: R6 showed
// occupancy was grid-limited at 2 blocks/CU) + register-prefetch double-buffer.
// RO=4 => plain [KC][64] W staging is conflict-free (lane stride 4 floats:
// 16 lanes span all 32 banks 2-way; the R5 4-way was stride-8 with RO=8).
__global__ __launch_bounds__(256, 2)
void pq_gemm_kernel(const float* __restrict__ x, int Cin, size_t bstride,
                    const float* __restrict__ W, int Cout,
                    float* __restrict__ p, float* __restrict__ q) {
    // grid: (Cout/64, NPTS/64, BATCH); block 256 = 16(tn:o) x 16(tm:n)
    int b = blockIdx.z;
    int o0 = blockIdx.x * 64;
    int n0 = blockIdx.y * 64;
    const float* xb = x + (size_t)b * bstride;
    __shared__ float W1s[KC][64];
    __shared__ float WQs[KC][64];
    __shared__ float Xs[KC][64];
    int tid = threadIdx.x;
    int tn = tid % 16;  // o = o0 + tn*4 + i
    int tm = tid / 16;  // n = n0 + tm*4 + j
    float accp[4][4] = {};
    float accq[4][4] = {};

    const int ix = tid * 4, ccx = ix >> 6, nnx = ix & 63;
    const int r = tid % 64, cg = (tid / 64) * 4;   // W row, cc-group of 4
    const float* Wr = W + (size_t)(o0 + r) * 2 * Cin;
    float4 px, pw1, pw2;
    auto prefetch = [&](int c0) {
        px = make_float4(0.f, 0.f, 0.f, 0.f);
        pw1 = make_float4(0.f, 0.f, 0.f, 0.f);
        pw2 = make_float4(0.f, 0.f, 0.f, 0.f);
        if (c0 + ccx < Cin) px = *(const float4*)(xb + (size_t)(c0 + ccx) * NPTS + n0 + nnx);
        if (c0 + cg < Cin) {   // all Cin are multiples of 4
            pw1 = *(const float4*)(Wr + c0 + cg);
            pw2 = *(const float4*)(Wr + Cin + c0 + cg);
        }
    };
    prefetch(0);
    for (int c0 = 0; c0 < Cin; c0 += KC) {
        *(float4*)(&Xs[ccx][nnx]) = px;
        W1s[cg + 0][r] = pw1.x; WQs[cg + 0][r] = pw2.x - pw1.x;
        W1s[cg + 1][r] = pw1.y; WQs[cg + 1][r] = pw2.y - pw1.y;
        W1s[cg + 2][r] = pw1.z; WQs[cg + 2][r] = pw2.z - pw1.z;
        W1s[cg + 3][r] = pw1.w; WQs[cg + 3][r] = pw2.w - pw1.w;
        __syncthreads();
        if (c0 + KC < Cin) prefetch(c0 + KC);
#pragma unroll
        for (int cc = 0; cc < KC; ++cc) {
            float4 wv = *(const float4*)(&W1s[cc][tn * 4]);
            float4 qv = *(const float4*)(&WQs[cc][tn * 4]);
            float4 xv = *(const float4*)(&Xs[cc][tm * 4]);
            float w1[4] = {wv.x, wv.y, wv.z, wv.w};
            float wq[4] = {qv.x, qv.y, qv.z, qv.w};
            float xj[4] = {xv.x, xv.y, xv.z, xv.w};
#pragma unroll
            for (int i = 0; i < 4; i++)
#pragma unroll
                for (int j = 0; j < 4; j++) {
                    accp[i][j] += w1[i] * xj[j];
                    accq[i][j] += wq[i] * xj[j];
                }
        }
        __syncthreads();
    }
    // ---- write out: for each of 4 n rows, 4 consecutive o floats ----
#pragma unroll
    for (int j = 0; j < 4; j++) {
        int n = n0 + tm * 4 + j;
        size_t base = ((size_t)b * NPTS + n) * Cout + o0 + tn * 4;
        *(float4*)(p + base) = make_float4(accp[0][j], accp[1][j], accp[2][j], accp[3][j]);
        *(float4*)(q + base) = make_float4(accq[0][j], accq[1][j], accq[2][j], accq[3][j]);
    }
}

// ---------------- stats pass 1: BN sum/sumsq (deterministic partials) ----------------
template <int COUT>
__global__ void stats_kernel(const float* __restrict__ p, const float* __restrict__ q,
                             const int* __restrict__ idx,
                             float* __restrict__ partials) {
    constexpr int CA = (COUT < 256) ? COUT : 256;
    constexpr int PP = 256 / CA;
    constexpr int NCH = COUT / CA;
    constexpr int NCHUNK = 16;
    int bid = blockIdx.x;
    int b = bid / (NPTS / NCHUNK);
    int n0 = (bid % (NPTS / NCHUNK)) * NCHUNK;
    int cl = threadIdx.x % CA;
    int c = blockIdx.y * CA + cl;
    int sub = threadIdx.x / CA;
    float s = 0.f, ss = 0.f;
    for (int nl = sub; nl < NCHUNK; nl += PP) {
        int n = n0 + nl;
        size_t nb = (size_t)b * NPTS + n;
        const int* ix = idx + nb * KNN;
        float qv = q[nb * COUT + c];
        for (int k = 0; k < KNN; ++k) {
            int m = ix[k];
            float v = p[((size_t)b * NPTS + m) * COUT + c] + qv;
            s += v;
            ss += v * v;
        }
    }
    __shared__ float red[256];
    float* outp = partials + ((size_t)bid * NCH + blockIdx.y) * 2 * CA;
    red[threadIdx.x] = s;
    __syncthreads();
    for (int st = PP / 2; st > 0; st >>= 1) {
        if (sub < st) red[threadIdx.x] += red[threadIdx.x + st * CA];
        __syncthreads();
    }
    if (sub == 0) outp[cl] = red[cl];
    __syncthreads();
    red[threadIdx.x] = ss;
    __syncthreads();
    for (int st = PP / 2; st > 0; st >>= 1) {
        if (sub < st) red[threadIdx.x] += red[threadIdx.x + st * CA];
        __syncthreads();
    }
    if (sub == 0) outp[CA + cl] = red[cl];
}

// ---------------- BN scale/shift from partials (deterministic serial reduce) ----------------
__global__ void scaleshift_kernel(const float* __restrict__ partials, const float* __restrict__ g,
                                  const float* __restrict__ beta, int Cout, int nblk,
                                  int CA, int NCH, float* __restrict__ sc) {
    int c = blockIdx.x * 256 + threadIdx.x;
    if (c >= Cout) return;
    int chunk = c / CA, within = c % CA;
    float s0 = 0.f, s1 = 0.f;
    for (int b = 0; b < nblk; ++b) {
        const float* pp = partials + ((size_t)b * NCH + chunk) * 2 * CA;
        s0 += pp[within];
        s1 += pp[CA + within];
    }
    float cnt = (float)(BATCH * NPTS * KNN);
    float mean = s0 / cnt;
    float var = s1 / cnt - mean * mean;
    float s = g[c] * rsqrtf(var + EPS);
    sc[c] = s;
    sc[Cout + c] = beta[c] - mean * s;
}

// ---------------- pass 2: gather max/min, BN+leaky, transpose to (B, C, N) feat ----------------
__global__ void apply_kernel(const float* __restrict__ p, const float* __restrict__ q,
                             const int* __restrict__ idx, const float* __restrict__ sc,
                             int Cout, int choff, float* __restrict__ feat) {
    // grid: (Cout/32, NPTS/32, BATCH); block 256 = 32 (c) x 8 (n-sub)
    __shared__ float tile[32][33];
    __shared__ int nidx[32][KNN];
    int b = blockIdx.z;
    int c0 = blockIdx.x * 32, n0 = blockIdx.y * 32;
    int tx = threadIdx.x % 32, ty = threadIdx.x / 32;
    for (int i = threadIdx.x; i < 32 * KNN; i += 256) {
        int nn = i / KNN, kk = i % KNN;
        nidx[nn][kk] = idx[((size_t)b * NPTS + n0 + nn) * KNN + kk];
    }
    __syncthreads();
    int c = c0 + tx;
    float s = sc[c], sh = sc[Cout + c];
    for (int i = ty; i < 32; i += 8) {
        int n = n0 + i;
        size_t nb = (size_t)b * NPTS + n;
        float qv = q[nb * Cout + c];
        float mx = -INFINITY, mn = INFINITY;
        for (int k = 0; k < KNN; ++k) {
            int m = nidx[i][k];
            float v = p[((size_t)b * NPTS + m) * Cout + c] + qv;
            mx = fmaxf(mx, v);
            mn = fminf(mn, v);
        }
        float v = (s >= 0.f) ? mx : mn;
        v = s * v + sh;
        tile[i][tx] = (v > 0.f) ? v : 0.2f * v;
    }
    __syncthreads();
    for (int i = ty; i < 32; i += 8) {
        feat[((size_t)b * FEATC + choff + c0 + i) * NPTS + n0 + tx] = tile[tx][i];
    }
}

// ---------------- pooling: max and mean over N ----------------
__global__ void pool_kernel(const float* __restrict__ feat, float* __restrict__ pooled) {
    // grid BATCH*FEATC, block 256
    int t = blockIdx.x;
    int b = t >> 11, c = t & (FEATC - 1);
    const float* row = feat + (size_t)t * NPTS;
    int tid = threadIdx.x;
    float mx = -INFINITY, sm = 0.f;
    for (int n = tid; n < NPTS; n += 256) { float v = row[n]; mx = fmaxf(mx, v); sm += v; }
    __shared__ float smx[256], ssm[256];
    smx[tid] = mx; ssm[tid] = sm;
    __syncthreads();
    for (int s = 128; s > 0; s >>= 1) {
        if (tid < s) { smx[tid] = fmaxf(smx[tid], smx[tid + s]); ssm[tid] += ssm[tid + s]; }
        __syncthreads();
    }
    if (tid == 0) {
        pooled[b * 4096 + c] = smx[0];
        pooled[b * 4096 + 2048 + c] = ssm[0] * (1.f / NPTS);
    }
}

// ---------------- final GEMV + batch-BN + leaky ----------------
__global__ void final_kernel(const float* __restrict__ pooled, const float* __restrict__ Wm,
                             const float* __restrict__ bm, const float* __restrict__ gm,
                             const float* __restrict__ betam, float* __restrict__ out) {
    // grid 512, block 256
    int o = blockIdx.x;
    int tid = threadIdx.x;
    float acc[BATCH] = {};
    for (int t = tid; t < 4096; t += 256) {
        float w = Wm[(size_t)o * 4096 + t];
#pragma unroll
        for (int b = 0; b < BATCH; b++) acc[b] += w * pooled[b * 4096 + t];
    }
    __shared__ float red[256];
    float zb[BATCH];
    for (int b = 0; b < BATCH; b++) {
        red[tid] = acc[b];
        __syncthreads();
        for (int s = 128; s > 0; s >>= 1) {
            if (tid < s) red[tid] += red[tid + s];
            __syncthreads();
        }
        zb[b] = red[0];
        __syncthreads();
    }
    if (tid == 0) {
        float z[BATCH];
        float mean = 0.f;
        for (int b = 0; b < BATCH; b++) { z[b] = zb[b] + bm[o]; mean += z[b]; }
        mean *= (1.f / BATCH);
        float var = 0.f;
        for (int b = 0; b < BATCH; b++) { float d = z[b] - mean; var += d * d; }
        var *= (1.f / BATCH);
        float s = gm[o] * rsqrtf(var + EPS);
        for (int b = 0; b < BATCH; b++) {
            float v = (z[b] - mean) * s + betam[o];
            out[b * 512 + o] = (v > 0.f) ? v : 0.2f * v;
        }
    }
}

extern "C" void kernel_launch(void* const* d_in, const int* in_sizes, int n_in,
                              void* d_out, int out_size, void* d_ws, size_t ws_size,
                              hipStream_t stream) {
    const float* x = (const float*)d_in[0];
    const float* Wm = (const float*)d_in[19];
    const float* bm = (const float*)d_in[20];
    const float* gm = (const float*)d_in[21];
    const float* betam = (const float*)d_in[22];
    float* out = (float*)d_out;

    char* ws = (char*)d_ws;
    // Compact layout — total 67 MB.
    float* G        = (float*)(ws);                                    // [0,16) MB (shared with p)
    float* p        = G;
    float* q        = (float*)(ws + (size_t)(16 << 20));               // [16,32) MB
    float* feat     = (float*)(ws + (size_t)(32 << 20));               // [32,64) MB
    int*   idx      = (int*)  (ws + (size_t)(64 << 20));               // 320 KB
    float* xx       = (float*)(ws + (size_t)(64 << 20) + (384 << 10)); // 16 KB
    float* sc       = (float*)(ws + (size_t)(64 << 20) + (448 << 10)); // 8 KB
    float* pooled   = (float*)(ws + (size_t)(64 << 20) + (512 << 10)); // 64 KB
    float* partials = (float*)(ws + (size_t)(65 << 20));               // [65,67) MB

    const int cins[6]   = {8, 64, 64, 128, 256, 512};
    const int couts[6]  = {64, 64, 128, 256, 512, 1024};
    const int choffs[6] = {0, 64, 128, 256, 512, 1024};

    const float* xin = x;
    size_t bstride = (size_t)8 * NPTS;
    const int NBLK = BATCH * (NPTS / 16);  // 256 n-chunk blocks for stats

    for (int L = 0; L < 6; ++L) {
        int Cin = cins[L], Cout = couts[L], choff = choffs[L];
        const float* W = (const float*)d_in[1 + 3 * L];
        const float* g = (const float*)d_in[2 + 3 * L];
        const float* bb = (const float*)d_in[3 + 3 * L];

        gram_kernel<<<dim3(NPTS / 128, NPTS / 64, BATCH), 256, 0, stream>>>(xin, Cin, bstride, G);
        diag_kernel<<<BATCH * NPTS / 256, 256, 0, stream>>>(G, xx);
        topk_kernel<<<BATCH * NPTS / 4, 256, 0, stream>>>(G, xx, idx);
        pq_gemm_kernel<<<dim3(Cout / 64, NPTS / 64, BATCH), 256, 0, stream>>>(xin, Cin, bstride, W, Cout, p, q);
        int CA = (Cout < 256) ? Cout : 256;
        int NCH = Cout / CA;
        switch (Cout) {
            case 64:   stats_kernel<64>  <<<dim3(NBLK, 1), 256, 0, stream>>>(p, q, idx, partials); break;
            case 128:  stats_kernel<128> <<<dim3(NBLK, 1), 256, 0, stream>>>(p, q, idx, partials); break;
            case 256:  stats_kernel<256> <<<dim3(NBLK, 1), 256, 0, stream>>>(p, q, idx, partials); break;
            case 512:  stats_kernel<512> <<<dim3(NBLK, 2), 256, 0, stream>>>(p, q, idx, partials); break;
            case 1024: stats_kernel<1024><<<dim3(NBLK, 4), 256, 0, stream>>>(p, q, idx, partials); break;
        }
        scaleshift_kernel<<<(Cout + 255) / 256, 256, 0, stream>>>(partials, g, bb, Cout, NBLK, CA, NCH, sc);
        apply_kernel<<<dim3(Cout / 32, NPTS / 32, BATCH), 256, 0, stream>>>(p, q, idx, sc, Cout, choff, feat);

        xin = feat + (size_t)choff * NPTS;
        bstride = (size_t)FEATC * NPTS;
    }

    pool_kernel<<<BATCH * FEATC, 256, 0, stream>>>(feat, pooled);
    final_kernel<<<512, 256, 0, stream>>>(pooled, Wm, bm, gm, betam, out);
}